// Round 2
// baseline (35723.502 us; speedup 1.0000x reference)
//
#include <hip/hip_runtime.h>

// ---------------------------------------------------------------------------
// 3-layer LayerNorm-GRU (haste style), B=32 T=512 IN=128 H=1024 OUT=80
// Round 9: two-hop sync, zero fences.
//   - 64 compute blocks x 16 h-cols (Rs 48x1024 fp16 = 99KB LDS), no
//     aggregator block: every block reduces pstat itself (128 in-flight
//     bypass loads) -> sfin hop removed from the critical path.
//   - NO acquire fence: h read via global_load_dwordx4 sc0 sc1 (LLC bypass,
//     pairs with producers' sc1 write-through), pstat via relaxed agent
//     atomic loads. L1/L2 stay warm for wx/biases/hs_out all 512 steps.
//   - per-wave flags (256 lines/barrier): each wave flags after wave-local
//     vmcnt(0); consumers poll 4 lines/lane. One __syncthreads per step
//     (rhp K-half combine); all other ordering via the flag protocol.
//   - thread owns 2 adjacent h-cols: u32 h publish, 4B hs_out store.
// ---------------------------------------------------------------------------

typedef float    f32x4 __attribute__((ext_vector_type(4)));
typedef _Float16 f16x8 __attribute__((ext_vector_type(8)));
typedef _Float16 f16x2 __attribute__((ext_vector_type(2)));

#define HH      1024
#define TT      512
#define BBATCH  32
#define H3      3072
#define MROWS   16384      // B*T
#define NBLK    64         // compute blocks (no aggregator)
#define HPB     16         // h-indices per block
#define COLS    48         // 3*HPB columns of R per block
#define LN_EPS  1e-5f

// ctrl region word offsets (128B line separation, 256 lines per flag set)
#define W_SEQA  0          // 256 lines * 32 words (pstat flags, line=wv*64+blk)
#define W_SEQB  8192       // 256 lines * 32 words (h flags)

// workspace layout (bytes)
#define OFF_CTRL   0u
#define OFF_PSTAT  65536u             // pstat[64][64] f32 = 16 KB
#define OFF_H      81920u             // h fp16 [32][1024] = 64 KB
#define OFF_HF     147456u            // h fp32 [32][1024] = 128 KB (ends 278528)
#define CTRL_BYTES 278528u            // memset region
#define OFF_WLB    327680u            // Wlin^T fp16 [80][1024]  = 160 KB
#define OFF_WB     524288u            // W^T fp16 [3072][K<=1024] = 6 MB
#define OFF_XBF    (8ull<<20)         // x fp16 [16384][128]     = 4 MB
#define OFF_WX     (16ull<<20)        // wx fp16 [16384][3072]   = 96 MB
#define OFF_HSA    (112ull<<20)       // hs fp16 [16384][1024]   = 32 MB
#define OFF_HSB    (144ull<<20)       // hs fp16 [16384][1024]   = 32 MB  (end 176 MB)

#define ALOAD(p)    __hip_atomic_load((p),  __ATOMIC_RELAXED, __HIP_MEMORY_SCOPE_AGENT)
#define ASTORE(p,v) __hip_atomic_store((p), (v), __ATOMIC_RELAXED, __HIP_MEMORY_SCOPE_AGENT)

// LLC-coherent 16B load (bypasses L1 via sc0 and L2 via sc1); pairs with
// producers' sc1 write-through stores. Caller must s_waitcnt vmcnt before use.
__device__ __forceinline__ f16x8 ldg_h16(const _Float16* p) {
  f16x8 r;
  asm volatile("global_load_dwordx4 %0, %1, off sc0 sc1" : "=v"(r) : "v"(p));
  return r;
}

// per-wave poll of 256 flag lines (4 per lane)
__device__ __forceinline__ void wave_wait4(const unsigned* seq, unsigned tgt, int lane) {
  const unsigned* p0 = seq + lane * 32;
  const unsigned* p1 = seq + (lane + 64) * 32;
  const unsigned* p2 = seq + (lane + 128) * 32;
  const unsigned* p3 = seq + (lane + 192) * 32;
  int spins = 0;
  for (;;) {
    const unsigned a = ALOAD(p0);
    const unsigned b = ALOAD(p1);
    const unsigned c = ALOAD(p2);
    const unsigned d = ALOAD(p3);
    if (__all((a >= tgt) & (b >= tgt) & (c >= tgt) & (d >= tgt))) break;
    __builtin_amdgcn_s_sleep(1);
    if (++spins > (1 << 24)) break;   // safety: wrong answer, not hang
  }
}

// ---------------------------------------------------------------------------
// init: x fp32 -> fp16 ; Wlin [1024][80] -> Wlb^T fp16 [80][1024]
__global__ __launch_bounds__(256, 1) void k_init(
    const float* __restrict__ x, _Float16* __restrict__ xb,
    const float* __restrict__ Wlin, _Float16* __restrict__ Wlb)
{
  const size_t stride = (size_t)gridDim.x * 256;
  for (size_t i = (size_t)blockIdx.x * 256 + threadIdx.x; i < (size_t)MROWS * 128; i += stride)
    xb[i] = (_Float16)x[i];
  for (size_t i = (size_t)blockIdx.x * 256 + threadIdx.x; i < 80u * 1024u; i += stride) {
    const size_t n = i >> 10, k = i & 1023u;
    Wlb[i] = (_Float16)Wlin[k * 80 + n];
  }
}

// W fp32 [K][3072] -> Wb fp16 [3072][K] (n-major for B-fragments)
__global__ __launch_bounds__(256, 1) void k_convW(
    const float* __restrict__ W, _Float16* __restrict__ Wb, const int K)
{
  const int n = blockIdx.x;
  for (int k = threadIdx.x; k < K; k += 256)
    Wb[(size_t)n * K + k] = (_Float16)W[(size_t)k * H3 + n];
}

// Cw[16384][3072] (fp16, raw pre-LN) = A[16384][K] @ W[K][3072]
__global__ __launch_bounds__(256, 1) void k_gemm(
    const _Float16* __restrict__ A,
    const _Float16* __restrict__ Bw,   // [3072][K]
    _Float16* __restrict__ Cw,
    const int K)
{
  __shared__ _Float16 Bs[64][40];
  const int tid = threadIdx.x;
  const int lane = tid & 63, wv = tid >> 6;
  const int l15 = lane & 15, quad = lane >> 4;
  const int tilem = blockIdx.x / 48, tilen = blockIdx.x % 48;
  const int mbase = tilem * 64 + wv * 16;
  const size_t nbase = (size_t)tilen * 64;
  f32x4 acc[4] = {{0.f,0.f,0.f,0.f},{0.f,0.f,0.f,0.f},{0.f,0.f,0.f,0.f},{0.f,0.f,0.f,0.f}};
  const _Float16* arow = A + (size_t)(mbase + l15) * K + quad * 8;
  const int sn = tid >> 2, sk = (tid & 3) * 8;
  const _Float16* bsrc = Bw + (nbase + sn) * K + sk;
  for (int kc = 0; kc < K; kc += 32) {
    __syncthreads();
    *(f16x8*)(&Bs[sn][sk]) = *(const f16x8*)(bsrc + kc);
    __syncthreads();
    const f16x8 af = *(const f16x8*)(arow + kc);
#pragma unroll
    for (int nt = 0; nt < 4; ++nt) {
      const f16x8 bv = *(const f16x8*)(&Bs[nt * 16 + l15][quad * 8]);
      acc[nt] = __builtin_amdgcn_mfma_f32_16x16x32_f16(af, bv, acc[nt], 0, 0, 0);
    }
  }
#pragma unroll
  for (int nt = 0; nt < 4; ++nt)
#pragma unroll
    for (int j = 0; j < 4; ++j)
      Cw[(size_t)(mbase + quad * 4 + j) * H3 + nbase + nt * 16 + l15] = (_Float16)acc[nt][j];
}

// in-place LayerNorm * gw over rows of wx (3072 cols), one row per wave
__global__ __launch_bounds__(256, 1) void k_ln(
    _Float16* __restrict__ wxp, const float* __restrict__ gw)
{
  const int wv = threadIdx.x >> 6, lane = threadIdx.x & 63;
  const size_t row = (size_t)blockIdx.x * 4 + wv;
  _Float16* p = wxp + row * H3 + lane * 8;
  float vals[48];
  float s = 0.f, q = 0.f;
#pragma unroll
  for (int c = 0; c < 6; ++c) {
    const f16x8 v = *(const f16x8*)(p + c * 512);
#pragma unroll
    for (int j = 0; j < 8; ++j) {
      const float f = (float)v[j];
      vals[c * 8 + j] = f; s += f; q += f * f;
    }
  }
#pragma unroll
  for (int m = 1; m < 64; m <<= 1) { s += __shfl_xor(s, m); q += __shfl_xor(q, m); }
  const float mean = s * (1.f / H3);
  const float var  = q * (1.f / H3) - mean * mean;
  const float inv  = rsqrtf(var + LN_EPS);
#pragma unroll
  for (int c = 0; c < 6; ++c) {
    f16x8 o;
#pragma unroll
    for (int j = 0; j < 8; ++j)
      o[j] = (_Float16)((vals[c * 8 + j] - mean) * inv * gw[c * 512 + lane * 8 + j]);
    *(f16x8*)(p + c * 512) = o;
  }
}

// ---------------------------------------------------------------------------
// recurrence: 512 steps, 64 blocks, no aggregator, two global hops per step
__global__ __launch_bounds__(256, 1) void k_recur(
    const float* __restrict__ R, const float* __restrict__ bx,
    const float* __restrict__ br, const float* __restrict__ gr,
    const _Float16* __restrict__ wx,
    _Float16* __restrict__ hs_out,
    unsigned* __restrict__ hglob,     // h fp16 [32][1024], sc1-stored as u32 pairs
    float* __restrict__ hf32,
    float* __restrict__ pstat,        // [64][64] partial stats (s,q per row)
    unsigned* __restrict__ ctrl,
    const unsigned abase,             // l*TT
    const unsigned hbase)             // l*(TT+1)
{
  const int tid = threadIdx.x;
  const int blk = blockIdx.x;
  unsigned* seqA = ctrl + W_SEQA;
  unsigned* seqB = ctrl + W_SEQB;

  __shared__ _Float16 Rs[COLS][HH + 8];
  __shared__ float rhp[2][BBATCH][52];    // K-half partials (48 cols + pad)

  const int lane = tid & 63;
  const int wv   = tid >> 6;
  const int mh   = wv >> 1;       // which 16 batch rows
  const int kh   = wv & 1;        // which K half (512)
  const int l15  = lane & 15;
  const int quad = lane >> 4;
  const int kb   = kh * 512;

  // load R slice (cols {i, H+i, 2H+i} for i in [blk*16, blk*16+16)), fp32->fp16
  for (int n = 0; n < COLS; ++n) {
    const int gc = (n >> 4) * HH + blk * HPB + (n & 15);
    for (int k = tid; k < HH; k += 256)
      Rs[n][k] = (_Float16)R[(size_t)k * H3 + gc];
  }

  // per-thread gate ownership: (batch row, 2 adjacent h-cols)
  const int b_row = tid >> 3;
  const int jj    = tid & 7;
  const int gi0   = blk * HPB + 2 * jj;
  const int gi1   = gi0 + 1;
  const float bxz0 = bx[gi0],          bxz1 = bx[gi1];
  const float bxr0 = bx[HH + gi0],     bxr1 = bx[HH + gi1];
  const float bxg0 = bx[2 * HH + gi0], bxg1 = bx[2 * HH + gi1];
  const float brz0 = br[gi0],          brz1 = br[gi1];
  const float brr0 = br[HH + gi0],     brr1 = br[HH + gi1];
  const float brg0 = br[2 * HH + gi0], brg1 = br[2 * HH + gi1];
  const float grz0 = gr[gi0],          grz1 = gr[gi1];
  const float grr0 = gr[HH + gi0],     grr1 = gr[HH + gi1];
  const float grg0 = gr[2 * HH + gi0], grg1 = gr[2 * HH + gi1];
  float hl0 = hf32[b_row * HH + gi0];
  float hl1 = hf32[b_row * HH + gi1];

  // initial coherent publish of own h pair (sc1 u32), per-wave flag hbase+1
  {
    union { _Float16 f[2]; unsigned u; } hp;
    hp.f[0] = (_Float16)hl0; hp.f[1] = (_Float16)hl1;
    ASTORE(&hglob[b_row * 512 + blk * 8 + jj], hp.u);
  }
  asm volatile("s_waitcnt vmcnt(0)" ::: "memory");
  if (lane == 0) ASTORE(&seqB[(wv * 64 + blk) * 32], hbase + 1u);
  __syncthreads();                 // Rs staging complete before first MFMA

  const _Float16* hrow = (const _Float16*)hglob
                       + (size_t)(mh * 16 + l15) * HH + kb + quad * 8;
  const float* pp = pstat + b_row * 2;

  for (int t = 0; t < TT; ++t) {
    // ---- wait for all 256 wave h-flags (each wave polls independently)
    wave_wait4(seqB, hbase + (unsigned)t + 1u, lane);
    __builtin_amdgcn_sched_barrier(0);

    // ---- phase 1: 16 LLC-bypass A loads fully in flight, then MFMA
    f16x8 af[16];
#pragma unroll
    for (int ks = 0; ks < 16; ++ks)
      af[ks] = ldg_h16(hrow + ks * 32);
    asm volatile("s_waitcnt vmcnt(0)" ::: "memory");
    __builtin_amdgcn_sched_barrier(0);

    f32x4 a0 = {0.f,0.f,0.f,0.f}, a1 = {0.f,0.f,0.f,0.f}, a2 = {0.f,0.f,0.f,0.f};
#pragma unroll
    for (int ks = 0; ks < 16; ++ks) {
      const f16x8 b0 = *(const f16x8*)(&Rs[l15][kb + ks * 32 + quad * 8]);
      a0 = __builtin_amdgcn_mfma_f32_16x16x32_f16(af[ks], b0, a0, 0, 0, 0);
      const f16x8 b1 = *(const f16x8*)(&Rs[16 + l15][kb + ks * 32 + quad * 8]);
      a1 = __builtin_amdgcn_mfma_f32_16x16x32_f16(af[ks], b1, a1, 0, 0, 0);
      const f16x8 b2 = *(const f16x8*)(&Rs[32 + l15][kb + ks * 32 + quad * 8]);
      a2 = __builtin_amdgcn_mfma_f32_16x16x32_f16(af[ks], b2, a2, 0, 0, 0);
    }
    // K-half partials (C layout: row=quad*4+j, col=l15)
#pragma unroll
    for (int j = 0; j < 4; ++j) {
      rhp[kh][mh * 16 + quad * 4 + j][l15]      = a0[j];
      rhp[kh][mh * 16 + quad * 4 + j][16 + l15] = a1[j];
      rhp[kh][mh * 16 + quad * 4 + j][32 + l15] = a2[j];
    }
    __syncthreads();   // the single per-step barrier

    // ---- combine K halves (own 2 cols); per-row stats via 8-lane butterfly
    const int i0 = 2 * jj, i1 = i0 + 1;
    const float rz0 = rhp[0][b_row][i0]      + rhp[1][b_row][i0];
    const float rz1 = rhp[0][b_row][i1]      + rhp[1][b_row][i1];
    const float rr0 = rhp[0][b_row][16 + i0] + rhp[1][b_row][16 + i0];
    const float rr1 = rhp[0][b_row][16 + i1] + rhp[1][b_row][16 + i1];
    const float rg0 = rhp[0][b_row][32 + i0] + rhp[1][b_row][32 + i0];
    const float rg1 = rhp[0][b_row][32 + i1] + rhp[1][b_row][32 + i1];
    {
      float s = (rz0 + rz1) + (rr0 + rr1) + (rg0 + rg1);
      float q = rz0 * rz0 + rz1 * rz1 + rr0 * rr0 + rr1 * rr1 + rg0 * rg0 + rg1 * rg1;
      s += __shfl_xor(s, 1); q += __shfl_xor(q, 1);
      s += __shfl_xor(s, 2); q += __shfl_xor(q, 2);
      s += __shfl_xor(s, 4); q += __shfl_xor(q, 4);
      // rows are wave-local: publish own rows' partials, flag per-wave
      if (jj == 0) ASTORE(&pstat[blk * 64 + b_row * 2], s);
      if (jj == 1) ASTORE(&pstat[blk * 64 + b_row * 2 + 1], q);
    }
    asm volatile("s_waitcnt vmcnt(0)" ::: "memory");
    if (lane == 0) ASTORE(&seqA[(wv * 64 + blk) * 32], abase + (unsigned)t + 1u);

    // prefetch phase-2 wx operands (L1/L2 warm: no fences in this kernel)
    const _Float16* wrow = wx + (size_t)(b_row * TT + t) * H3;
    const f16x2 wzv = *(const f16x2*)(wrow + gi0);
    const f16x2 wrv = *(const f16x2*)(wrow + HH + gi0);
    const f16x2 wgv = *(const f16x2*)(wrow + 2 * HH + gi0);

    // ---- wait for all 256 wave pstat-flags; reduce 64 blocks in-flight
    wave_wait4(seqA, abase + (unsigned)t + 1u, lane);
    __builtin_amdgcn_sched_barrier(0);
    float s0 = 0.f, s1 = 0.f, q0 = 0.f, q1 = 0.f;
#pragma unroll
    for (int b2 = 0; b2 < NBLK; b2 += 2) {
      s0 += ALOAD(pp + b2 * 64);      q0 += ALOAD(pp + b2 * 64 + 1);
      s1 += ALOAD(pp + b2 * 64 + 64); q1 += ALOAD(pp + b2 * 64 + 65);
    }
    const float sfs = s0 + s1, sfq = q0 + q1;

    // ---- phase 2: finalize LN, gates, h update (2 cols)
    const float mean = sfs * (1.f / H3);
    const float var  = sfq * (1.f / H3) - mean * mean;
    const float inv  = rsqrtf(var + LN_EPS);
    const float rzn0 = (rz0 - mean) * inv * grz0, rzn1 = (rz1 - mean) * inv * grz1;
    const float rrn0 = (rr0 - mean) * inv * grr0, rrn1 = (rr1 - mean) * inv * grr1;
    const float rgn0 = (rg0 - mean) * inv * grg0, rgn1 = (rg1 - mean) * inv * grg1;
    const float zg0 = 1.f / (1.f + __expf(-((float)wzv[0] + bxz0 + rzn0 + brz0)));
    const float zg1 = 1.f / (1.f + __expf(-((float)wzv[1] + bxz1 + rzn1 + brz1)));
    const float rga0 = 1.f / (1.f + __expf(-((float)wrv[0] + bxr0 + rrn0 + brr0)));
    const float rga1 = 1.f / (1.f + __expf(-((float)wrv[1] + bxr1 + rrn1 + brr1)));
    const float gg0 = tanhf((float)wgv[0] + bxg0 + rga0 * (rgn0 + brg0));
    const float gg1 = tanhf((float)wgv[1] + bxg1 + rga1 * (rgn1 + brg1));
    const float hn0 = zg0 * hl0 + (1.f - zg0) * gg0;
    const float hn1 = zg1 * hl1 + (1.f - zg1) * gg1;
    hl0 = hn0; hl1 = hn1;
    union { _Float16 f[2]; unsigned u; } hp;
    hp.f[0] = (_Float16)hn0; hp.f[1] = (_Float16)hn1;
    ASTORE(&hglob[b_row * 512 + blk * 8 + jj], hp.u);          // sc1 h publish
    *(f16x2*)(&hs_out[(size_t)(b_row * TT + t) * HH + gi0]) =
        *(const f16x2*)hp.f;                                   // cached (kernel-boundary)
    asm volatile("s_waitcnt vmcnt(0)" ::: "memory");
    if (lane == 0) ASTORE(&seqB[(wv * 64 + blk) * 32], hbase + (unsigned)t + 2u);
  }
  hf32[b_row * HH + gi0] = hl0;   // fp32 handoff to next layer (cached)
  hf32[b_row * HH + gi1] = hl1;
}

// ---------------------------------------------------------------------------
// out[16384][80] = tanh(hs @ Wlin + blin)
__global__ __launch_bounds__(256, 1) void k_proj(
    const _Float16* __restrict__ hs,
    const _Float16* __restrict__ Wlb,   // [80][1024] fp16
    const float* __restrict__ blin,
    float* __restrict__ out)
{
  const int tid = threadIdx.x, lane = tid & 63, wv = tid >> 6;
  const int l15 = lane & 15, quad = lane >> 4;
  const int mbase = blockIdx.x * 64 + wv * 16;
  f32x4 acc[5] = {{0.f,0.f,0.f,0.f},{0.f,0.f,0.f,0.f},{0.f,0.f,0.f,0.f},
                  {0.f,0.f,0.f,0.f},{0.f,0.f,0.f,0.f}};
  const _Float16* arow = hs + (size_t)(mbase + l15) * HH + quad * 8;
  for (int kc = 0; kc < HH; kc += 32) {
    const f16x8 af = *(const f16x8*)(arow + kc);
#pragma unroll
    for (int nt = 0; nt < 5; ++nt) {
      const f16x8 bv = *(const f16x8*)(Wlb + (size_t)(nt * 16 + l15) * HH + kc + quad * 8);
      acc[nt] = __builtin_amdgcn_mfma_f32_16x16x32_f16(af, bv, acc[nt], 0, 0, 0);
    }
  }
#pragma unroll
  for (int nt = 0; nt < 5; ++nt)
#pragma unroll
    for (int j = 0; j < 4; ++j) {
      const int col = nt * 16 + l15;
      out[(size_t)(mbase + quad * 4 + j) * 80 + col] = tanhf(acc[nt][j] + blin[col]);
    }
}

// ---------------------------------------------------------------------------
extern "C" void kernel_launch(void* const* d_in, const int* in_sizes, int n_in,
                              void* d_out, int out_size, void* d_ws, size_t ws_size,
                              hipStream_t stream)
{
  const float* x    = (const float*)d_in[0];
  const float* W0   = (const float*)d_in[1];
  const float* R0   = (const float*)d_in[2];
  const float* bx0  = (const float*)d_in[3];
  const float* br0  = (const float*)d_in[4];
  const float* gw0  = (const float*)d_in[5];
  const float* gr0  = (const float*)d_in[6];
  const float* Wk   = (const float*)d_in[7];
  const float* Rk   = (const float*)d_in[8];
  const float* bxk  = (const float*)d_in[9];
  const float* brk  = (const float*)d_in[10];
  const float* gwk  = (const float*)d_in[11];
  const float* grk  = (const float*)d_in[12];
  const float* Wlin = (const float*)d_in[13];
  const float* blin = (const float*)d_in[14];

  char* ws = (char*)d_ws;
  unsigned*  ctrl   = (unsigned*)(ws + OFF_CTRL);
  float*     pstat  = (float*)(ws + OFF_PSTAT);
  unsigned*  hglob  = (unsigned*)(ws + OFF_H);
  float*     hf32   = (float*)(ws + OFF_HF);
  _Float16*  Wlb    = (_Float16*)(ws + OFF_WLB);
  _Float16*  Wb     = (_Float16*)(ws + OFF_WB);
  _Float16*  xb     = (_Float16*)(ws + OFF_XBF);
  _Float16*  wx     = (_Float16*)(ws + OFF_WX);
  _Float16*  hsA    = (_Float16*)(ws + OFF_HSA);
  _Float16*  hsB    = (_Float16*)(ws + OFF_HSB);

  hipMemsetAsync(d_ws, 0, CTRL_BYTES, stream);   // flags, pstat, h state

  k_init<<<2048, 256, 0, stream>>>(x, xb, Wlin, Wlb);

  for (int l = 0; l < 3; ++l) {
    const int K = l ? HH : 128;
    const float* Wl  = l ? (Wk  + (size_t)(l - 1) * HH * H3) : W0;
    const float* Rl  = l ? (Rk  + (size_t)(l - 1) * HH * H3) : R0;
    const float* bxl = l ? (bxk + (size_t)(l - 1) * H3) : bx0;
    const float* brl = l ? (brk + (size_t)(l - 1) * H3) : br0;
    const float* gwl = l ? (gwk + (size_t)(l - 1) * H3) : gw0;
    const float* grl = l ? (grk + (size_t)(l - 1) * H3) : gr0;
    const _Float16* Ain = (l == 0) ? xb : ((l == 1) ? hsA : hsB);
    _Float16* hs_out = (l == 1) ? hsB : hsA;

    k_convW<<<H3, 256, 0, stream>>>(Wl, Wb, K);
    k_gemm<<<12288, 256, 0, stream>>>(Ain, Wb, wx, K);
    k_ln<<<4096, 256, 0, stream>>>(wx, gwl);
    k_recur<<<NBLK, 256, 0, stream>>>(Rl, bxl, brl, grl, wx, hs_out,
                                      hglob, hf32, pstat, ctrl,
                                      (unsigned)l * (unsigned)TT,
                                      (unsigned)l * (TT + 1u));
  }
  k_proj<<<256, 256, 0, stream>>>(hsA, Wlb, blin, (float*)d_out);
}

// Round 3
// 19544.632 us; speedup vs baseline: 1.8278x; 1.8278x over previous
//
#include <hip/hip_runtime.h>

// ---------------------------------------------------------------------------
// 3-layer LayerNorm-GRU (haste style), B=32 T=512 IN=128 H=1024 OUT=80
// Round 10: R8 skeleton (proven 6838us/layer) + two surgical changes.
//   - counter barriers: producers global_atomic_add after barrier-drained
//     publish; consumers poll ONE line (tid0) then __syncthreads. Poll
//     traffic ~128x lower than flag arrays -> kills LLC poll storms that
//     caused 26-41ms straggler dispatches in R8/R9.
//   - flat pstat allreduce: no aggregator block. Each block reads
//     pstat[128][64] (32KB) with 8 coalesced dwordx4 sc0sc1 loads/thread
//     (single LLC latency exposure) + 2-level LDS tree. Deletes the
//     aggregator's two relay sub-hops (~2us/step).
//   Everything else byte-identical to R8: 128 blocks, K-split waves,
//   af[16] register prefetch, acquire(inv)+cached h loads, sc1 publishes,
//   barrier-implied vmcnt(0) before flags/adds.
// ---------------------------------------------------------------------------

typedef float    f32x4 __attribute__((ext_vector_type(4)));
typedef _Float16 f16x8 __attribute__((ext_vector_type(8)));

#define HH      1024
#define TT      512
#define BBATCH  32
#define H3      3072
#define MROWS   16384      // B*T
#define NBLK_R  128        // compute blocks
#define HPB     8          // h-indices per recurrence block
#define COLS    24         // 3*HPB columns of R per block
#define LN_EPS  1e-5f

// workspace layout (bytes)
#define OFF_CTRL   0u                 // cntA @ word0, cntB @ word32
#define OFF_PSTAT  4096u              // pstat[128][64] f32 = 32 KB (ends 36864)
#define OFF_H      40960u             // h fp16 [32][1024] = 64 KB
#define OFF_HF     106496u            // h fp32 [32][1024] = 128 KB (ends 237568)
#define CTRL_BYTES 237568u            // memset region
#define OFF_WLB    327680u            // Wlin^T fp16 [80][1024]  = 160 KB
#define OFF_WB     524288u            // W^T fp16 [3072][K<=1024] = 6 MB
#define OFF_XBF    (8ull<<20)         // x fp16 [16384][128]     = 4 MB
#define OFF_WX     (16ull<<20)        // wx fp16 [16384][3072]   = 96 MB
#define OFF_HSA    (112ull<<20)       // hs fp16 [16384][1024]   = 32 MB
#define OFF_HSB    (144ull<<20)       // hs fp16 [16384][1024]   = 32 MB  (end 176 MB)

#define ALOAD(p)    __hip_atomic_load((p),  __ATOMIC_RELAXED, __HIP_MEMORY_SCOPE_AGENT)
#define ASTORE(p,v) __hip_atomic_store((p), (v), __ATOMIC_RELAXED, __HIP_MEMORY_SCOPE_AGENT)
#define AADD(p)     __hip_atomic_fetch_add((p), 1u, __ATOMIC_RELAXED, __HIP_MEMORY_SCOPE_AGENT)

// single-line counter poll (broadcast-friendly; caller barriers after)
__device__ __forceinline__ void cons_wait(const unsigned* cnt, unsigned tgt) {
  int spins = 0;
  while (ALOAD(cnt) < tgt) {
    __builtin_amdgcn_s_sleep(1);
    if (++spins > (1 << 24)) break;   // safety: wrong answer, not hang
  }
}

// LLC-coherent 16B load (bypasses L1/L2); caller must s_waitcnt vmcnt first
__device__ __forceinline__ f32x4 ldg_f32x4(const float* p) {
  f32x4 r;
  asm volatile("global_load_dwordx4 %0, %1, off sc0 sc1" : "=v"(r) : "v"(p));
  return r;
}

// ---------------------------------------------------------------------------
// init: x fp32 -> fp16 ; Wlin [1024][80] -> Wlb^T fp16 [80][1024]
__global__ __launch_bounds__(256, 1) void k_init(
    const float* __restrict__ x, _Float16* __restrict__ xb,
    const float* __restrict__ Wlin, _Float16* __restrict__ Wlb)
{
  const size_t stride = (size_t)gridDim.x * 256;
  for (size_t i = (size_t)blockIdx.x * 256 + threadIdx.x; i < (size_t)MROWS * 128; i += stride)
    xb[i] = (_Float16)x[i];
  for (size_t i = (size_t)blockIdx.x * 256 + threadIdx.x; i < 80u * 1024u; i += stride) {
    const size_t n = i >> 10, k = i & 1023u;
    Wlb[i] = (_Float16)Wlin[k * 80 + n];
  }
}

// W fp32 [K][3072] -> Wb fp16 [3072][K] (n-major for B-fragments)
__global__ __launch_bounds__(256, 1) void k_convW(
    const float* __restrict__ W, _Float16* __restrict__ Wb, const int K)
{
  const int n = blockIdx.x;
  for (int k = threadIdx.x; k < K; k += 256)
    Wb[(size_t)n * K + k] = (_Float16)W[(size_t)k * H3 + n];
}

// Cw[16384][3072] (fp16, raw pre-LN) = A[16384][K] @ W[K][3072]
__global__ __launch_bounds__(256, 1) void k_gemm(
    const _Float16* __restrict__ A,
    const _Float16* __restrict__ Bw,   // [3072][K]
    _Float16* __restrict__ Cw,
    const int K)
{
  __shared__ _Float16 Bs[64][40];
  const int tid = threadIdx.x;
  const int lane = tid & 63, wv = tid >> 6;
  const int l15 = lane & 15, quad = lane >> 4;
  const int tilem = blockIdx.x / 48, tilen = blockIdx.x % 48;
  const int mbase = tilem * 64 + wv * 16;
  const size_t nbase = (size_t)tilen * 64;
  f32x4 acc[4] = {{0.f,0.f,0.f,0.f},{0.f,0.f,0.f,0.f},{0.f,0.f,0.f,0.f},{0.f,0.f,0.f,0.f}};
  const _Float16* arow = A + (size_t)(mbase + l15) * K + quad * 8;
  const int sn = tid >> 2, sk = (tid & 3) * 8;
  const _Float16* bsrc = Bw + (nbase + sn) * K + sk;
  for (int kc = 0; kc < K; kc += 32) {
    __syncthreads();
    *(f16x8*)(&Bs[sn][sk]) = *(const f16x8*)(bsrc + kc);
    __syncthreads();
    const f16x8 af = *(const f16x8*)(arow + kc);
#pragma unroll
    for (int nt = 0; nt < 4; ++nt) {
      const f16x8 bv = *(const f16x8*)(&Bs[nt * 16 + l15][quad * 8]);
      acc[nt] = __builtin_amdgcn_mfma_f32_16x16x32_f16(af, bv, acc[nt], 0, 0, 0);
    }
  }
#pragma unroll
  for (int nt = 0; nt < 4; ++nt)
#pragma unroll
    for (int j = 0; j < 4; ++j)
      Cw[(size_t)(mbase + quad * 4 + j) * H3 + nbase + nt * 16 + l15] = (_Float16)acc[nt][j];
}

// in-place LayerNorm * gw over rows of wx (3072 cols), one row per wave
__global__ __launch_bounds__(256, 1) void k_ln(
    _Float16* __restrict__ wxp, const float* __restrict__ gw)
{
  const int wv = threadIdx.x >> 6, lane = threadIdx.x & 63;
  const size_t row = (size_t)blockIdx.x * 4 + wv;
  _Float16* p = wxp + row * H3 + lane * 8;
  float vals[48];
  float s = 0.f, q = 0.f;
#pragma unroll
  for (int c = 0; c < 6; ++c) {
    const f16x8 v = *(const f16x8*)(p + c * 512);
#pragma unroll
    for (int j = 0; j < 8; ++j) {
      const float f = (float)v[j];
      vals[c * 8 + j] = f; s += f; q += f * f;
    }
  }
#pragma unroll
  for (int m = 1; m < 64; m <<= 1) { s += __shfl_xor(s, m); q += __shfl_xor(q, m); }
  const float mean = s * (1.f / H3);
  const float var  = q * (1.f / H3) - mean * mean;
  const float inv  = rsqrtf(var + LN_EPS);
#pragma unroll
  for (int c = 0; c < 6; ++c) {
    f16x8 o;
#pragma unroll
    for (int j = 0; j < 8; ++j)
      o[j] = (_Float16)((vals[c * 8 + j] - mean) * inv * gw[c * 512 + lane * 8 + j]);
    *(f16x8*)(p + c * 512) = o;
  }
}

// ---------------------------------------------------------------------------
// recurrence: 512 steps, 128 blocks, counter barriers, flat stats allreduce
__global__ __launch_bounds__(256, 1) void k_recur(
    const float* __restrict__ R, const float* __restrict__ bx,
    const float* __restrict__ br, const float* __restrict__ gr,
    const _Float16* __restrict__ wx,
    _Float16* __restrict__ hs_out,
    unsigned* __restrict__ hglob,     // h fp16 [32][1024], sc1-stored as u32 pairs
    float* __restrict__ hf32,
    float* __restrict__ pstat,        // [128][64] partial stats
    unsigned* __restrict__ ctrl,
    const unsigned abase,             // l*TT
    const unsigned hbase)             // l*(TT+1)
{
  const int tid = threadIdx.x;
  const int blk = blockIdx.x;
  unsigned* cntA = ctrl + 0;    // stats-published counter (line 0)
  unsigned* cntB = ctrl + 32;   // h-published counter (line 1)

  __shared__ _Float16 Rs[COLS][HH + 8];
  __shared__ float rhp[2][BBATCH][26];    // K-half partials
  __shared__ float statb[BBATCH][2];
  __shared__ float pred[16][64];          // pstat row-group partials
  __shared__ float sredf[64];             // final reduced stats

  const int lane = tid & 63;
  const int wv   = tid >> 6;
  const int mh   = wv >> 1;       // which 16 batch rows
  const int kh   = wv & 1;        // which K half (512)
  const int l15  = lane & 15;
  const int quad = lane >> 4;
  const int kb   = kh * 512;

  // load R slice (cols {i, H+i, 2H+i} for i in [blk*8, blk*8+8)), fp32->fp16
  for (int n = 0; n < COLS; ++n) {
    const int gc = (n >> 3) * HH + blk * HPB + (n & 7);
    for (int k = tid; k < HH; k += 256)
      Rs[n][k] = (_Float16)R[(size_t)k * H3 + gc];
  }

  // per-thread gate ownership: (batch row, h-index)
  const int b_row = tid >> 3;
  const int jj    = tid & 7;
  const int gi    = blk * HPB + jj;
  const float bxz = bx[gi], bxr = bx[HH + gi], bxg = bx[2 * HH + gi];
  const float brz = br[gi], brr = br[HH + gi], brg = br[2 * HH + gi];
  const float grz = gr[gi], grr = gr[HH + gi], grg = gr[2 * HH + gi];
  float hloc = hf32[b_row * HH + gi];

  // initial coherent publish of own h slice (sc1 u32 pairs)
  {
    union { _Float16 f; unsigned short s; } hc; hc.f = (_Float16)hloc;
    const unsigned short mybits = hc.s;
    const unsigned short pbits  = (unsigned short)__shfl_xor((int)mybits, 1);
    if ((jj & 1) == 0) {
      const unsigned w = (unsigned)mybits | ((unsigned)pbits << 16);
      ASTORE(&hglob[b_row * 512 + blk * 4 + (jj >> 1)], w);
    }
  }
  __syncthreads();                 // drains all waves' vmcnt before the add
  if (tid == 0) AADD(cntB);

  const _Float16* hread = (const _Float16*)hglob;
  const _Float16* hrow  = hread + (size_t)(mh * 16 + l15) * HH + kb + quad * 8;
  const int n1 = 16 + (l15 & 7);          // ntile1 row (lanes >=8 read dup, masked)

  for (int t = 0; t < TT; ++t) {
    // ---- wait for all 128 h publishes (single-line poll)
    if (tid == 0) cons_wait(cntB, 128u * (hbase + (unsigned)t + 1u));
    __syncthreads();
    __builtin_amdgcn_fence(__ATOMIC_ACQUIRE, "agent");   // inv only (no wbl2)

    // ---- phase 1: A-operand prefetch (16 loads fully in flight), then MFMA
    f16x8 af[16];
#pragma unroll
    for (int ks = 0; ks < 16; ++ks)
      af[ks] = *(const f16x8*)(hrow + ks * 32);
    f32x4 acc0 = {0.f,0.f,0.f,0.f}, acc1 = {0.f,0.f,0.f,0.f};
#pragma unroll
    for (int ks = 0; ks < 16; ++ks) {
      const f16x8 b0 = *(const f16x8*)(&Rs[l15][kb + ks * 32 + quad * 8]);
      acc0 = __builtin_amdgcn_mfma_f32_16x16x32_f16(af[ks], b0, acc0, 0, 0, 0);
      const f16x8 b1 = *(const f16x8*)(&Rs[n1][kb + ks * 32 + quad * 8]);
      acc1 = __builtin_amdgcn_mfma_f32_16x16x32_f16(af[ks], b1, acc1, 0, 0, 0);
    }
    // write K-half partials (C layout: row=quad*4+j, col=l15)
#pragma unroll
    for (int j = 0; j < 4; ++j) {
      rhp[kh][mh * 16 + quad * 4 + j][l15] = acc0[j];
      if (l15 < 8) rhp[kh][mh * 16 + quad * 4 + j][16 + l15] = acc1[j];
    }
    __syncthreads();

    // ---- combine K halves; per-row LN partial stats (8-thread shfl reduce)
    const float rz = rhp[0][b_row][jj]      + rhp[1][b_row][jj];
    const float rr = rhp[0][b_row][8 + jj]  + rhp[1][b_row][8 + jj];
    const float rg = rhp[0][b_row][16 + jj] + rhp[1][b_row][16 + jj];
    {
      float s = rz + rr + rg;
      float q = rz * rz + rr * rr + rg * rg;
      s += __shfl_xor(s, 1); q += __shfl_xor(q, 1);
      s += __shfl_xor(s, 2); q += __shfl_xor(q, 2);
      s += __shfl_xor(s, 4); q += __shfl_xor(q, 4);
      if (jj == 0) { statb[b_row][0] = s; statb[b_row][1] = q; }
    }
    __syncthreads();
    // publish pstat (wave 0 only; wave-local s_waitcnt orders add after data)
    if (tid < 64) ASTORE(&pstat[blk * 64 + tid], statb[tid >> 1][tid & 1]);
    asm volatile("s_waitcnt vmcnt(0)" ::: "memory");
    if (tid == 0) AADD(cntA);

    // prefetch phase-2 wx operands while stats converge
    const _Float16* wrow = wx + (size_t)(b_row * TT + t) * H3;
    const float wz = (float)wrow[gi];
    const float wr = (float)wrow[HH + gi];
    const float wg = (float)wrow[2 * HH + gi];

    // ---- wait for all 128 pstat publishes (single-line poll)
    if (tid == 0) cons_wait(cntA, 128u * (abase + (unsigned)t + 1u));
    __syncthreads();

    // ---- flat allreduce: 8 coalesced bypass dwordx4 loads, all in flight
    {
      const int prow0 = tid >> 4;          // 0..15
      const int pcol  = (tid & 15) * 4;    // 0..60
      f32x4 pv0 = ldg_f32x4(pstat + (size_t)(prow0      ) * 64 + pcol);
      f32x4 pv1 = ldg_f32x4(pstat + (size_t)(prow0 +  16) * 64 + pcol);
      f32x4 pv2 = ldg_f32x4(pstat + (size_t)(prow0 +  32) * 64 + pcol);
      f32x4 pv3 = ldg_f32x4(pstat + (size_t)(prow0 +  48) * 64 + pcol);
      f32x4 pv4 = ldg_f32x4(pstat + (size_t)(prow0 +  64) * 64 + pcol);
      f32x4 pv5 = ldg_f32x4(pstat + (size_t)(prow0 +  80) * 64 + pcol);
      f32x4 pv6 = ldg_f32x4(pstat + (size_t)(prow0 +  96) * 64 + pcol);
      f32x4 pv7 = ldg_f32x4(pstat + (size_t)(prow0 + 112) * 64 + pcol);
      asm volatile("s_waitcnt vmcnt(0)" ::: "memory");
      const f32x4 pa = ((pv0 + pv1) + (pv2 + pv3)) + ((pv4 + pv5) + (pv6 + pv7));
      *(f32x4*)(&pred[prow0][pcol]) = pa;
    }
    __syncthreads();
    if (tid < 64) {
      float acc = 0.f;
#pragma unroll
      for (int g = 0; g < 16; ++g) acc += pred[g][tid];
      sredf[tid] = acc;
    }
    __syncthreads();
    const float sfs = sredf[b_row * 2 + 0];
    const float sfq = sredf[b_row * 2 + 1];

    // ---- phase 2: finalize LN, gates, h update
    const float mean = sfs * (1.f / H3);
    const float var  = sfq * (1.f / H3) - mean * mean;
    const float inv  = rsqrtf(var + LN_EPS);
    const float rzn = (rz - mean) * inv * grz;
    const float rrn = (rr - mean) * inv * grr;
    const float rgn = (rg - mean) * inv * grg;
    const float zg    = 1.f / (1.f + __expf(-(wz + bxz + rzn + brz)));
    const float rgate = 1.f / (1.f + __expf(-(wr + bxr + rrn + brr)));
    const float gg    = tanhf(wg + bxg + rgate * (rgn + brg));
    const float hn = zg * hloc + (1.f - zg) * gg;
    hloc = hn;
    union { _Float16 f; unsigned short s; } hc; hc.f = (_Float16)hn;
    const unsigned short mybits = hc.s;
    const unsigned short pbits  = (unsigned short)__shfl_xor((int)mybits, 1);
    if ((jj & 1) == 0) {
      const unsigned w = (unsigned)mybits | ((unsigned)pbits << 16);
      ASTORE(&hglob[b_row * 512 + blk * 4 + (jj >> 1)], w);   // sc1 h publish
    }
    hs_out[(size_t)(b_row * TT + t) * HH + gi] = hc.f;        // cached (kernel-boundary)
    __syncthreads();                 // drains all waves' vmcnt before the add
    if (tid == 0) AADD(cntB);
  }
  hf32[b_row * HH + gi] = hloc;   // fp32 handoff to next layer (cached)
}

// ---------------------------------------------------------------------------
// out[16384][80] = tanh(hs @ Wlin + blin)
__global__ __launch_bounds__(256, 1) void k_proj(
    const _Float16* __restrict__ hs,
    const _Float16* __restrict__ Wlb,   // [80][1024] fp16
    const float* __restrict__ blin,
    float* __restrict__ out)
{
  const int tid = threadIdx.x, lane = tid & 63, wv = tid >> 6;
  const int l15 = lane & 15, quad = lane >> 4;
  const int mbase = blockIdx.x * 64 + wv * 16;
  f32x4 acc[5] = {{0.f,0.f,0.f,0.f},{0.f,0.f,0.f,0.f},{0.f,0.f,0.f,0.f},
                  {0.f,0.f,0.f,0.f},{0.f,0.f,0.f,0.f}};
  const _Float16* arow = hs + (size_t)(mbase + l15) * HH + quad * 8;
  for (int kc = 0; kc < HH; kc += 32) {
    const f16x8 af = *(const f16x8*)(arow + kc);
#pragma unroll
    for (int nt = 0; nt < 5; ++nt) {
      const f16x8 bv = *(const f16x8*)(Wlb + (size_t)(nt * 16 + l15) * HH + kc + quad * 8);
      acc[nt] = __builtin_amdgcn_mfma_f32_16x16x32_f16(af, bv, acc[nt], 0, 0, 0);
    }
  }
#pragma unroll
  for (int nt = 0; nt < 5; ++nt)
#pragma unroll
    for (int j = 0; j < 4; ++j) {
      const int col = nt * 16 + l15;
      out[(size_t)(mbase + quad * 4 + j) * 80 + col] = tanhf(acc[nt][j] + blin[col]);
    }
}

// ---------------------------------------------------------------------------
extern "C" void kernel_launch(void* const* d_in, const int* in_sizes, int n_in,
                              void* d_out, int out_size, void* d_ws, size_t ws_size,
                              hipStream_t stream)
{
  const float* x    = (const float*)d_in[0];
  const float* W0   = (const float*)d_in[1];
  const float* R0   = (const float*)d_in[2];
  const float* bx0  = (const float*)d_in[3];
  const float* br0  = (const float*)d_in[4];
  const float* gw0  = (const float*)d_in[5];
  const float* gr0  = (const float*)d_in[6];
  const float* Wk   = (const float*)d_in[7];
  const float* Rk   = (const float*)d_in[8];
  const float* bxk  = (const float*)d_in[9];
  const float* brk  = (const float*)d_in[10];
  const float* gwk  = (const float*)d_in[11];
  const float* grk  = (const float*)d_in[12];
  const float* Wlin = (const float*)d_in[13];
  const float* blin = (const float*)d_in[14];

  char* ws = (char*)d_ws;
  unsigned*  ctrl   = (unsigned*)(ws + OFF_CTRL);
  float*     pstat  = (float*)(ws + OFF_PSTAT);
  unsigned*  hglob  = (unsigned*)(ws + OFF_H);
  float*     hf32   = (float*)(ws + OFF_HF);
  _Float16*  Wlb    = (_Float16*)(ws + OFF_WLB);
  _Float16*  Wb     = (_Float16*)(ws + OFF_WB);
  _Float16*  xb     = (_Float16*)(ws + OFF_XBF);
  _Float16*  wx     = (_Float16*)(ws + OFF_WX);
  _Float16*  hsA    = (_Float16*)(ws + OFF_HSA);
  _Float16*  hsB    = (_Float16*)(ws + OFF_HSB);

  hipMemsetAsync(d_ws, 0, CTRL_BYTES, stream);   // counters, pstat, h state

  k_init<<<2048, 256, 0, stream>>>(x, xb, Wlin, Wlb);

  for (int l = 0; l < 3; ++l) {
    const int K = l ? HH : 128;
    const float* Wl  = l ? (Wk  + (size_t)(l - 1) * HH * H3) : W0;
    const float* Rl  = l ? (Rk  + (size_t)(l - 1) * HH * H3) : R0;
    const float* bxl = l ? (bxk + (size_t)(l - 1) * H3) : bx0;
    const float* brl = l ? (brk + (size_t)(l - 1) * H3) : br0;
    const float* gwl = l ? (gwk + (size_t)(l - 1) * H3) : gw0;
    const float* grl = l ? (grk + (size_t)(l - 1) * H3) : gr0;
    const _Float16* Ain = (l == 0) ? xb : ((l == 1) ? hsA : hsB);
    _Float16* hs_out = (l == 1) ? hsB : hsA;

    k_convW<<<H3, 256, 0, stream>>>(Wl, Wb, K);
    k_gemm<<<12288, 256, 0, stream>>>(Ain, Wb, wx, K);
    k_ln<<<4096, 256, 0, stream>>>(wx, gwl);
    k_recur<<<NBLK_R, 256, 0, stream>>>(Rl, bxl, brl, grl, wx, hs_out,
                                        hglob, hf32, pstat, ctrl,
                                        (unsigned)l * (unsigned)TT,
                                        (unsigned)l * (TT + 1u));
  }
  k_proj<<<256, 256, 0, stream>>>(hsA, Wlb, blin, (float*)d_out);
}

// Round 4
// 12958.751 us; speedup vs baseline: 2.7567x; 1.5082x over previous
//
#include <hip/hip_runtime.h>

// ---------------------------------------------------------------------------
// 3-layer LayerNorm-GRU (haste style), B=32 T=512 IN=128 H=1024 OUT=80
// Round 11: de-serialize the barriers, drop the per-step L2 invalidate.
//   - sharded counter barriers: 8 lines per event, block blk adds to line
//     blk&7 -> RMW queue depth 16 (was 128, ~2us of serialization per
//     barrier paid by the last arriver). tid<8 poll tight (no s_sleep).
//   - NO acquire fence: h read via global_load_dwordx4 sc0 sc1 (LLC,
//     pairs with producers' sc1 stores). wx / hs_out / biases stay
//     L2-resident across all 512 steps (was: invalidated every step).
//   - per-wave h publish: each wave does wave-local vmcnt(0) + lane0 add
//     (4 adds/block/event, 64/line). Removes the full-drain barrier.
//   - 5 __syncthreads/step (was 7); broadcast-read stats finish (no tree).
//   - rcp-sigmoid, expf-tanh (no libm tanhf on critical path).
//   Protocol invariants preserved: data sc1-stores -> wave-local vmcnt(0)
//   -> counter add; consumer poll -> barrier -> LLC-coherent reads.
// ---------------------------------------------------------------------------

typedef float    f32x4 __attribute__((ext_vector_type(4)));
typedef _Float16 f16x8 __attribute__((ext_vector_type(8)));

#define HH      1024
#define TT      512
#define BBATCH  32
#define H3      3072
#define MROWS   16384      // B*T
#define NBLK_R  128        // compute blocks
#define HPB     8          // h-indices per recurrence block
#define COLS    24         // 3*HPB columns of R per block
#define LN_EPS  1e-5f

// workspace layout (bytes)
#define OFF_CTRL   0u                 // cntA lines 0..7, cntB lines 8..15
#define OFF_PSTAT  4096u              // pstat[128][64] f32 = 32 KB
#define OFF_H      36864u             // h fp16 [32][1024] = 64 KB
#define OFF_HF     102400u            // h fp32 [32][1024] = 128 KB (ends 233472)
#define CTRL_BYTES 233472u            // memset region
#define OFF_WLB    327680u            // Wlin^T fp16 [80][1024]  = 160 KB
#define OFF_WB     524288u            // W^T fp16 [3072][K<=1024] = 6 MB
#define OFF_XBF    (8ull<<20)         // x fp16 [16384][128]     = 4 MB
#define OFF_WX     (16ull<<20)        // wx fp16 [16384][3072]   = 96 MB
#define OFF_HSA    (112ull<<20)       // hs fp16 [16384][1024]   = 32 MB
#define OFF_HSB    (144ull<<20)       // hs fp16 [16384][1024]   = 32 MB  (end 176 MB)

#define ALOAD(p)    __hip_atomic_load((p),  __ATOMIC_RELAXED, __HIP_MEMORY_SCOPE_AGENT)
#define ASTORE(p,v) __hip_atomic_store((p), (v), __ATOMIC_RELAXED, __HIP_MEMORY_SCOPE_AGENT)
#define AADD(p)     __hip_atomic_fetch_add((p), 1u, __ATOMIC_RELAXED, __HIP_MEMORY_SCOPE_AGENT)

// LLC-coherent 16B loads (bypass L1 via sc0, L2 via sc1); caller waits vmcnt
__device__ __forceinline__ f16x8 ldg_h16(const _Float16* p) {
  f16x8 r;
  asm volatile("global_load_dwordx4 %0, %1, off sc0 sc1" : "=v"(r) : "v"(p));
  return r;
}
__device__ __forceinline__ f32x4 ldg_f32x4(const float* p) {
  f32x4 r;
  asm volatile("global_load_dwordx4 %0, %1, off sc0 sc1" : "=v"(r) : "v"(p));
  return r;
}

__device__ __forceinline__ float sigf(float x) {
  return __builtin_amdgcn_rcpf(1.f + __expf(-x));
}
__device__ __forceinline__ float tanhfast(float x) {
  const float e2 = __expf(2.f * x);       // x->+inf: rcp(inf)=0 -> 1; x->-inf: -1
  return 1.f - 2.f * __builtin_amdgcn_rcpf(e2 + 1.f);
}

// ---------------------------------------------------------------------------
// init: x fp32 -> fp16 ; Wlin [1024][80] -> Wlb^T fp16 [80][1024]
__global__ __launch_bounds__(256, 1) void k_init(
    const float* __restrict__ x, _Float16* __restrict__ xb,
    const float* __restrict__ Wlin, _Float16* __restrict__ Wlb)
{
  const size_t stride = (size_t)gridDim.x * 256;
  for (size_t i = (size_t)blockIdx.x * 256 + threadIdx.x; i < (size_t)MROWS * 128; i += stride)
    xb[i] = (_Float16)x[i];
  for (size_t i = (size_t)blockIdx.x * 256 + threadIdx.x; i < 80u * 1024u; i += stride) {
    const size_t n = i >> 10, k = i & 1023u;
    Wlb[i] = (_Float16)Wlin[k * 80 + n];
  }
}

// W fp32 [K][3072] -> Wb fp16 [3072][K] (n-major for B-fragments)
__global__ __launch_bounds__(256, 1) void k_convW(
    const float* __restrict__ W, _Float16* __restrict__ Wb, const int K)
{
  const int n = blockIdx.x;
  for (int k = threadIdx.x; k < K; k += 256)
    Wb[(size_t)n * K + k] = (_Float16)W[(size_t)k * H3 + n];
}

// Cw[16384][3072] (fp16, raw pre-LN) = A[16384][K] @ W[K][3072]
__global__ __launch_bounds__(256, 1) void k_gemm(
    const _Float16* __restrict__ A,
    const _Float16* __restrict__ Bw,   // [3072][K]
    _Float16* __restrict__ Cw,
    const int K)
{
  __shared__ _Float16 Bs[64][40];
  const int tid = threadIdx.x;
  const int lane = tid & 63, wv = tid >> 6;
  const int l15 = lane & 15, quad = lane >> 4;
  const int tilem = blockIdx.x / 48, tilen = blockIdx.x % 48;
  const int mbase = tilem * 64 + wv * 16;
  const size_t nbase = (size_t)tilen * 64;
  f32x4 acc[4] = {{0.f,0.f,0.f,0.f},{0.f,0.f,0.f,0.f},{0.f,0.f,0.f,0.f},{0.f,0.f,0.f,0.f}};
  const _Float16* arow = A + (size_t)(mbase + l15) * K + quad * 8;
  const int sn = tid >> 2, sk = (tid & 3) * 8;
  const _Float16* bsrc = Bw + (nbase + sn) * K + sk;
  for (int kc = 0; kc < K; kc += 32) {
    __syncthreads();
    *(f16x8*)(&Bs[sn][sk]) = *(const f16x8*)(bsrc + kc);
    __syncthreads();
    const f16x8 af = *(const f16x8*)(arow + kc);
#pragma unroll
    for (int nt = 0; nt < 4; ++nt) {
      const f16x8 bv = *(const f16x8*)(&Bs[nt * 16 + l15][quad * 8]);
      acc[nt] = __builtin_amdgcn_mfma_f32_16x16x32_f16(af, bv, acc[nt], 0, 0, 0);
    }
  }
#pragma unroll
  for (int nt = 0; nt < 4; ++nt)
#pragma unroll
    for (int j = 0; j < 4; ++j)
      Cw[(size_t)(mbase + quad * 4 + j) * H3 + nbase + nt * 16 + l15] = (_Float16)acc[nt][j];
}

// in-place LayerNorm * gw over rows of wx (3072 cols), one row per wave
__global__ __launch_bounds__(256, 1) void k_ln(
    _Float16* __restrict__ wxp, const float* __restrict__ gw)
{
  const int wv = threadIdx.x >> 6, lane = threadIdx.x & 63;
  const size_t row = (size_t)blockIdx.x * 4 + wv;
  _Float16* p = wxp + row * H3 + lane * 8;
  float vals[48];
  float s = 0.f, q = 0.f;
#pragma unroll
  for (int c = 0; c < 6; ++c) {
    const f16x8 v = *(const f16x8*)(p + c * 512);
#pragma unroll
    for (int j = 0; j < 8; ++j) {
      const float f = (float)v[j];
      vals[c * 8 + j] = f; s += f; q += f * f;
    }
  }
#pragma unroll
  for (int m = 1; m < 64; m <<= 1) { s += __shfl_xor(s, m); q += __shfl_xor(q, m); }
  const float mean = s * (1.f / H3);
  const float var  = q * (1.f / H3) - mean * mean;
  const float inv  = rsqrtf(var + LN_EPS);
#pragma unroll
  for (int c = 0; c < 6; ++c) {
    f16x8 o;
#pragma unroll
    for (int j = 0; j < 8; ++j)
      o[j] = (_Float16)((vals[c * 8 + j] - mean) * inv * gw[c * 512 + lane * 8 + j]);
    *(f16x8*)(p + c * 512) = o;
  }
}

// ---------------------------------------------------------------------------
// recurrence: 512 steps, 128 blocks, sharded counter barriers, no fences
__global__ __launch_bounds__(256, 1) void k_recur(
    const float* __restrict__ R, const float* __restrict__ bx,
    const float* __restrict__ br, const float* __restrict__ gr,
    const _Float16* __restrict__ wx,
    _Float16* __restrict__ hs_out,
    unsigned* __restrict__ hglob,     // h fp16 [32][1024], sc1-stored as u32 pairs
    float* __restrict__ hf32,
    float* __restrict__ pstat,        // [128][64] partial stats
    unsigned* __restrict__ ctrl,
    const unsigned abase,             // l*TT
    const unsigned hbase)             // l*(TT+1)
{
  const int tid = threadIdx.x;
  const int blk = blockIdx.x;
  unsigned* cntA = ctrl;              // 8 lines, word stride 32
  unsigned* cntB = ctrl + 256;        // 8 lines, word stride 32

  __shared__ _Float16 Rs[COLS][HH + 8];
  __shared__ float rhp[2][BBATCH][27];    // K-half partials (odd stride)
  __shared__ float statb[BBATCH][2];
  __shared__ float pred[16][68];          // pstat row-group partials

  const int lane = tid & 63;
  const int wv   = tid >> 6;
  const int mh   = wv >> 1;       // which 16 batch rows
  const int kh   = wv & 1;        // which K half (512)
  const int l15  = lane & 15;
  const int quad = lane >> 4;
  const int kb   = kh * 512;

  // load R slice (cols {i, H+i, 2H+i} for i in [blk*8, blk*8+8)), fp32->fp16
  for (int n = 0; n < COLS; ++n) {
    const int gc = (n >> 3) * HH + blk * HPB + (n & 7);
    for (int k = tid; k < HH; k += 256)
      Rs[n][k] = (_Float16)R[(size_t)k * H3 + gc];
  }

  // per-thread gate ownership: (batch row, h-index)
  const int b_row = tid >> 3;
  const int jj    = tid & 7;
  const int gi    = blk * HPB + jj;
  const float bxz = bx[gi], bxr = bx[HH + gi], bxg = bx[2 * HH + gi];
  const float brz = br[gi], brr = br[HH + gi], brg = br[2 * HH + gi];
  const float grz = gr[gi], grr = gr[HH + gi], grg = gr[2 * HH + gi];
  float hloc = hf32[b_row * HH + gi];

  // initial coherent publish of own h slice (sc1 u32 pairs), per-wave flag
  {
    union { _Float16 f; unsigned short s; } hc; hc.f = (_Float16)hloc;
    const unsigned short mybits = hc.s;
    const unsigned short pbits  = (unsigned short)__shfl_xor((int)mybits, 1);
    if ((jj & 1) == 0) {
      const unsigned w = (unsigned)mybits | ((unsigned)pbits << 16);
      ASTORE(&hglob[b_row * 512 + blk * 4 + (jj >> 1)], w);
    }
  }
  asm volatile("s_waitcnt vmcnt(0)" ::: "memory");   // wave-local drain
  if (lane == 0) AADD(&cntB[(blk & 7) * 32]);

  const _Float16* hread = (const _Float16*)hglob;
  const _Float16* hrow  = hread + (size_t)(mh * 16 + l15) * HH + kb + quad * 8;
  const int n1 = 16 + (l15 & 7);          // ntile1 row (lanes >=8 read dup, masked)

  for (int t = 0; t < TT; ++t) {
    // prefetch phase-2 wx operands (t-only dependence; L2-resident now)
    const _Float16* wrow = wx + (size_t)(b_row * TT + t) * H3;
    const float wz = (float)wrow[gi];
    const float wr = (float)wrow[HH + gi];
    const float wg = (float)wrow[2 * HH + gi];

    // ---- wait for all 512 wave h-publishes (8 sharded lines, tight poll)
    if (tid < 8) {
      const unsigned* p = cntB + tid * 32;
      const unsigned tgt = 64u * (hbase + (unsigned)t + 1u);
      int spins = 0;
      while (ALOAD(p) < tgt) { if (++spins > (1 << 24)) break; }
    }
    __syncthreads();                                   // barrier 1

    // ---- phase 1: 16 LLC-coherent A loads fully in flight, then MFMA
    f16x8 af[16];
#pragma unroll
    for (int ks = 0; ks < 16; ++ks)
      af[ks] = ldg_h16(hrow + ks * 32);
    asm volatile("s_waitcnt vmcnt(0)" ::: "memory");
    f32x4 acc0 = {0.f,0.f,0.f,0.f}, acc1 = {0.f,0.f,0.f,0.f};
#pragma unroll
    for (int ks = 0; ks < 16; ++ks) {
      const f16x8 b0 = *(const f16x8*)(&Rs[l15][kb + ks * 32 + quad * 8]);
      acc0 = __builtin_amdgcn_mfma_f32_16x16x32_f16(af[ks], b0, acc0, 0, 0, 0);
      const f16x8 b1 = *(const f16x8*)(&Rs[n1][kb + ks * 32 + quad * 8]);
      acc1 = __builtin_amdgcn_mfma_f32_16x16x32_f16(af[ks], b1, acc1, 0, 0, 0);
    }
    // write K-half partials (C layout: row=quad*4+j, col=l15)
#pragma unroll
    for (int j = 0; j < 4; ++j) {
      rhp[kh][mh * 16 + quad * 4 + j][l15] = acc0[j];
      if (l15 < 8) rhp[kh][mh * 16 + quad * 4 + j][16 + l15] = acc1[j];
    }
    __syncthreads();                                   // barrier 2

    // ---- combine K halves; per-row LN partial stats (8-thread shfl reduce)
    const float rz = rhp[0][b_row][jj]      + rhp[1][b_row][jj];
    const float rr = rhp[0][b_row][8 + jj]  + rhp[1][b_row][8 + jj];
    const float rg = rhp[0][b_row][16 + jj] + rhp[1][b_row][16 + jj];
    {
      float s = rz + rr + rg;
      float q = rz * rz + rr * rr + rg * rg;
      s += __shfl_xor(s, 1); q += __shfl_xor(q, 1);
      s += __shfl_xor(s, 2); q += __shfl_xor(q, 2);
      s += __shfl_xor(s, 4); q += __shfl_xor(q, 4);
      if (jj == 0) { statb[b_row][0] = s; statb[b_row][1] = q; }
    }
    __syncthreads();                                   // barrier 3
    // publish pstat (wave 0 only; wave-local drain orders add after data)
    if (tid < 64) ASTORE(&pstat[blk * 64 + tid], statb[tid >> 1][tid & 1]);
    asm volatile("s_waitcnt vmcnt(0)" ::: "memory");
    if (tid == 0) AADD(&cntA[(blk & 7) * 32]);

    // ---- wait for all 128 pstat publishes (8 sharded lines)
    if (tid < 8) {
      const unsigned* p = cntA + tid * 32;
      const unsigned tgt = 16u * (abase + (unsigned)t + 1u);
      int spins = 0;
      while (ALOAD(p) < tgt) { if (++spins > (1 << 24)) break; }
    }
    __syncthreads();                                   // barrier 4

    // ---- flat allreduce: 8 coalesced bypass dwordx4 loads, all in flight
    {
      const int prow0 = tid >> 4;          // 0..15
      const int pcol  = (tid & 15) * 4;    // 0..60
      f32x4 pv0 = ldg_f32x4(pstat + (size_t)(prow0      ) * 64 + pcol);
      f32x4 pv1 = ldg_f32x4(pstat + (size_t)(prow0 +  16) * 64 + pcol);
      f32x4 pv2 = ldg_f32x4(pstat + (size_t)(prow0 +  32) * 64 + pcol);
      f32x4 pv3 = ldg_f32x4(pstat + (size_t)(prow0 +  48) * 64 + pcol);
      f32x4 pv4 = ldg_f32x4(pstat + (size_t)(prow0 +  64) * 64 + pcol);
      f32x4 pv5 = ldg_f32x4(pstat + (size_t)(prow0 +  80) * 64 + pcol);
      f32x4 pv6 = ldg_f32x4(pstat + (size_t)(prow0 +  96) * 64 + pcol);
      f32x4 pv7 = ldg_f32x4(pstat + (size_t)(prow0 + 112) * 64 + pcol);
      asm volatile("s_waitcnt vmcnt(0)" ::: "memory");
      const f32x4 pa = ((pv0 + pv1) + (pv2 + pv3)) + ((pv4 + pv5) + (pv6 + pv7));
      *(f32x4*)(&pred[prow0][pcol]) = pa;
    }
    __syncthreads();                                   // barrier 5
    // broadcast-read finish: 16 group-partials for own row (same-addr bcast)
    float sfs = 0.f, sfq = 0.f;
#pragma unroll
    for (int g = 0; g < 16; ++g) {
      sfs += pred[g][2 * b_row];
      sfq += pred[g][2 * b_row + 1];
    }

    // ---- phase 2: finalize LN, gates, h update
    const float mean = sfs * (1.f / H3);
    const float var  = sfq * (1.f / H3) - mean * mean;
    const float inv  = __frsqrt_rn(var + LN_EPS);
    const float rzn = (rz - mean) * inv * grz;
    const float rrn = (rr - mean) * inv * grr;
    const float rgn = (rg - mean) * inv * grg;
    const float zg    = sigf(wz + bxz + rzn + brz);
    const float rgate = sigf(wr + bxr + rrn + brr);
    const float gg    = tanhfast(wg + bxg + rgate * (rgn + brg));
    const float hn = zg * hloc + (1.f - zg) * gg;
    hloc = hn;
    union { _Float16 f; unsigned short s; } hc; hc.f = (_Float16)hn;
    const unsigned short mybits = hc.s;
    const unsigned short pbits  = (unsigned short)__shfl_xor((int)mybits, 1);
    if ((jj & 1) == 0) {
      const unsigned w = (unsigned)mybits | ((unsigned)pbits << 16);
      ASTORE(&hglob[b_row * 512 + blk * 4 + (jj >> 1)], w);   // sc1 h publish
    }
    hs_out[(size_t)(b_row * TT + t) * HH + gi] = hc.f;        // L2-cached
    asm volatile("s_waitcnt vmcnt(0)" ::: "memory");          // wave-local drain
    if (lane == 0) AADD(&cntB[(blk & 7) * 32]);               // per-wave flag
  }
  hf32[b_row * HH + gi] = hloc;   // fp32 handoff to next layer (cached)
}

// ---------------------------------------------------------------------------
// out[16384][80] = tanh(hs @ Wlin + blin)
__global__ __launch_bounds__(256, 1) void k_proj(
    const _Float16* __restrict__ hs,
    const _Float16* __restrict__ Wlb,   // [80][1024] fp16
    const float* __restrict__ blin,
    float* __restrict__ out)
{
  const int tid = threadIdx.x, lane = tid & 63, wv = tid >> 6;
  const int l15 = lane & 15, quad = lane >> 4;
  const int mbase = blockIdx.x * 64 + wv * 16;
  f32x4 acc[5] = {{0.f,0.f,0.f,0.f},{0.f,0.f,0.f,0.f},{0.f,0.f,0.f,0.f},
                  {0.f,0.f,0.f,0.f},{0.f,0.f,0.f,0.f}};
  const _Float16* arow = hs + (size_t)(mbase + l15) * HH + quad * 8;
  for (int kc = 0; kc < HH; kc += 32) {
    const f16x8 af = *(const f16x8*)(arow + kc);
#pragma unroll
    for (int nt = 0; nt < 5; ++nt) {
      const f16x8 bv = *(const f16x8*)(Wlb + (size_t)(nt * 16 + l15) * HH + kc + quad * 8);
      acc[nt] = __builtin_amdgcn_mfma_f32_16x16x32_f16(af, bv, acc[nt], 0, 0, 0);
    }
  }
#pragma unroll
  for (int nt = 0; nt < 5; ++nt)
#pragma unroll
    for (int j = 0; j < 4; ++j) {
      const int col = nt * 16 + l15;
      out[(size_t)(mbase + quad * 4 + j) * 80 + col] = tanhf(acc[nt][j] + blin[col]);
    }
}

// ---------------------------------------------------------------------------
extern "C" void kernel_launch(void* const* d_in, const int* in_sizes, int n_in,
                              void* d_out, int out_size, void* d_ws, size_t ws_size,
                              hipStream_t stream)
{
  const float* x    = (const float*)d_in[0];
  const float* W0   = (const float*)d_in[1];
  const float* R0   = (const float*)d_in[2];
  const float* bx0  = (const float*)d_in[3];
  const float* br0  = (const float*)d_in[4];
  const float* gw0  = (const float*)d_in[5];
  const float* gr0  = (const float*)d_in[6];
  const float* Wk   = (const float*)d_in[7];
  const float* Rk   = (const float*)d_in[8];
  const float* bxk  = (const float*)d_in[9];
  const float* brk  = (const float*)d_in[10];
  const float* gwk  = (const float*)d_in[11];
  const float* grk  = (const float*)d_in[12];
  const float* Wlin = (const float*)d_in[13];
  const float* blin = (const float*)d_in[14];

  char* ws = (char*)d_ws;
  unsigned*  ctrl   = (unsigned*)(ws + OFF_CTRL);
  float*     pstat  = (float*)(ws + OFF_PSTAT);
  unsigned*  hglob  = (unsigned*)(ws + OFF_H);
  float*     hf32   = (float*)(ws + OFF_HF);
  _Float16*  Wlb    = (_Float16*)(ws + OFF_WLB);
  _Float16*  Wb     = (_Float16*)(ws + OFF_WB);
  _Float16*  xb     = (_Float16*)(ws + OFF_XBF);
  _Float16*  wx     = (_Float16*)(ws + OFF_WX);
  _Float16*  hsA    = (_Float16*)(ws + OFF_HSA);
  _Float16*  hsB    = (_Float16*)(ws + OFF_HSB);

  hipMemsetAsync(d_ws, 0, CTRL_BYTES, stream);   // counters, pstat, h state

  k_init<<<2048, 256, 0, stream>>>(x, xb, Wlin, Wlb);

  for (int l = 0; l < 3; ++l) {
    const int K = l ? HH : 128;
    const float* Wl  = l ? (Wk  + (size_t)(l - 1) * HH * H3) : W0;
    const float* Rl  = l ? (Rk  + (size_t)(l - 1) * HH * H3) : R0;
    const float* bxl = l ? (bxk + (size_t)(l - 1) * H3) : bx0;
    const float* brl = l ? (brk + (size_t)(l - 1) * H3) : br0;
    const float* gwl = l ? (gwk + (size_t)(l - 1) * H3) : gw0;
    const float* grl = l ? (grk + (size_t)(l - 1) * H3) : gr0;
    const _Float16* Ain = (l == 0) ? xb : ((l == 1) ? hsA : hsB);
    _Float16* hs_out = (l == 1) ? hsB : hsA;

    k_convW<<<H3, 256, 0, stream>>>(Wl, Wb, K);
    k_gemm<<<12288, 256, 0, stream>>>(Ain, Wb, wx, K);
    k_ln<<<4096, 256, 0, stream>>>(wx, gwl);
    k_recur<<<NBLK_R, 256, 0, stream>>>(Rl, bxl, brl, grl, wx, hs_out,
                                        hglob, hf32, pstat, ctrl,
                                        (unsigned)l * (unsigned)TT,
                                        (unsigned)l * (TT + 1u));
  }
  k_proj<<<256, 256, 0, stream>>>(hsA, Wlb, blin, (float*)d_out);
}

// Round 8
// 11124.113 us; speedup vs baseline: 3.2114x; 1.1649x over previous
//
#include <hip/hip_runtime.h>

// ---------------------------------------------------------------------------
// 3-layer LayerNorm-GRU (haste style), B=32 T=512 IN=128 H=1024 OUT=80
// Round 14: R11 protocol BIT-IDENTICAL (proven 4071us/layer, passing) +
// block-major hglob layout.
//   Post-mortem R12/R13: the shfl-based stats publish/gather failed twice
//   (absmax 1.9/1.7) across two independent implementations; design class
//   abandoned. R11's LDS-staged stats path (statb + pred tree) restored.
//   NEW (layout only, no protocol change): hglob is [128 blocks][32 rows]
//   [4 u32] block-major. Producer wave's publish = ONE full 128B line
//   (was 32 scattered 16B partial-line write-throughs per block) -> 8x
//   fewer LLC line transactions on the h hop's producer side. Consumer
//   af[ks] fragment = contiguous 16B at (kh*64+ks*4+quad)*512B + row*16B;
//   16 consecutive lanes -> 16 consecutive chunks (coalescing preserved).
// ---------------------------------------------------------------------------

typedef float    f32x4 __attribute__((ext_vector_type(4)));
typedef _Float16 f16x8 __attribute__((ext_vector_type(8)));

#define HH      1024
#define TT      512
#define BBATCH  32
#define H3      3072
#define MROWS   16384      // B*T
#define NBLK_R  128        // compute blocks
#define HPB     8          // h-indices per recurrence block
#define COLS    24         // 3*HPB columns of R per block
#define LN_EPS  1e-5f

// workspace layout (bytes)
#define OFF_CTRL   0u                 // cntA lines 0..7, cntB lines 8..15
#define OFF_PSTAT  4096u              // pstat[128][64] f32 = 32 KB
#define OFF_H      36864u             // h fp16 block-major [128][32][8] = 64 KB
#define OFF_HF     102400u            // h fp32 [32][1024] = 128 KB (ends 233472)
#define CTRL_BYTES 233472u            // memset region
#define OFF_WLB    327680u            // Wlin^T fp16 [80][1024]  = 160 KB
#define OFF_WB     524288u            // W^T fp16 [3072][K<=1024] = 6 MB
#define OFF_XBF    (8ull<<20)         // x fp16 [16384][128]     = 4 MB
#define OFF_WX     (16ull<<20)        // wx fp16 [16384][3072]   = 96 MB
#define OFF_HSA    (112ull<<20)       // hs fp16 [16384][1024]   = 32 MB
#define OFF_HSB    (144ull<<20)       // hs fp16 [16384][1024]   = 32 MB  (end 176 MB)

#define ALOAD(p)    __hip_atomic_load((p),  __ATOMIC_RELAXED, __HIP_MEMORY_SCOPE_AGENT)
#define ASTORE(p,v) __hip_atomic_store((p), (v), __ATOMIC_RELAXED, __HIP_MEMORY_SCOPE_AGENT)
#define AADD(p)     __hip_atomic_fetch_add((p), 1u, __ATOMIC_RELAXED, __HIP_MEMORY_SCOPE_AGENT)

// LLC-coherent loads (bypass L1 via sc0, L2 via sc1); caller waits vmcnt
__device__ __forceinline__ f16x8 ldg_h16(const _Float16* p) {
  f16x8 r;
  asm volatile("global_load_dwordx4 %0, %1, off sc0 sc1" : "=v"(r) : "v"(p));
  return r;
}
__device__ __forceinline__ f32x4 ldg_f32x4(const float* p) {
  f32x4 r;
  asm volatile("global_load_dwordx4 %0, %1, off sc0 sc1" : "=v"(r) : "v"(p));
  return r;
}

__device__ __forceinline__ float sigf(float x) {
  return __builtin_amdgcn_rcpf(1.f + __expf(-x));
}
__device__ __forceinline__ float tanhfast(float x) {
  const float e2 = __expf(2.f * x);
  return 1.f - 2.f * __builtin_amdgcn_rcpf(e2 + 1.f);
}

// ---------------------------------------------------------------------------
// init: x fp32 -> fp16 ; Wlin [1024][80] -> Wlb^T fp16 [80][1024]
__global__ __launch_bounds__(256, 1) void k_init(
    const float* __restrict__ x, _Float16* __restrict__ xb,
    const float* __restrict__ Wlin, _Float16* __restrict__ Wlb)
{
  const size_t stride = (size_t)gridDim.x * 256;
  for (size_t i = (size_t)blockIdx.x * 256 + threadIdx.x; i < (size_t)MROWS * 128; i += stride)
    xb[i] = (_Float16)x[i];
  for (size_t i = (size_t)blockIdx.x * 256 + threadIdx.x; i < 80u * 1024u; i += stride) {
    const size_t n = i >> 10, k = i & 1023u;
    Wlb[i] = (_Float16)Wlin[k * 80 + n];
  }
}

// W fp32 [K][3072] -> Wb fp16 [3072][K] (n-major for B-fragments)
__global__ __launch_bounds__(256, 1) void k_convW(
    const float* __restrict__ W, _Float16* __restrict__ Wb, const int K)
{
  const int n = blockIdx.x;
  for (int k = threadIdx.x; k < K; k += 256)
    Wb[(size_t)n * K + k] = (_Float16)W[(size_t)k * H3 + n];
}

// Cw[16384][3072] (fp16, raw pre-LN) = A[16384][K] @ W[K][3072]
__global__ __launch_bounds__(256, 1) void k_gemm(
    const _Float16* __restrict__ A,
    const _Float16* __restrict__ Bw,   // [3072][K]
    _Float16* __restrict__ Cw,
    const int K)
{
  __shared__ _Float16 Bs[64][40];
  const int tid = threadIdx.x;
  const int lane = tid & 63, wv = tid >> 6;
  const int l15 = lane & 15, quad = lane >> 4;
  const int tilem = blockIdx.x / 48, tilen = blockIdx.x % 48;
  const int mbase = tilem * 64 + wv * 16;
  const size_t nbase = (size_t)tilen * 64;
  f32x4 acc[4] = {{0.f,0.f,0.f,0.f},{0.f,0.f,0.f,0.f},{0.f,0.f,0.f,0.f},{0.f,0.f,0.f,0.f}};
  const _Float16* arow = A + (size_t)(mbase + l15) * K + quad * 8;
  const int sn = tid >> 2, sk = (tid & 3) * 8;
  const _Float16* bsrc = Bw + (nbase + sn) * K + sk;
  for (int kc = 0; kc < K; kc += 32) {
    __syncthreads();
    *(f16x8*)(&Bs[sn][sk]) = *(const f16x8*)(bsrc + kc);
    __syncthreads();
    const f16x8 af = *(const f16x8*)(arow + kc);
#pragma unroll
    for (int nt = 0; nt < 4; ++nt) {
      const f16x8 bv = *(const f16x8*)(&Bs[nt * 16 + l15][quad * 8]);
      acc[nt] = __builtin_amdgcn_mfma_f32_16x16x32_f16(af, bv, acc[nt], 0, 0, 0);
    }
  }
#pragma unroll
  for (int nt = 0; nt < 4; ++nt)
#pragma unroll
    for (int j = 0; j < 4; ++j)
      Cw[(size_t)(mbase + quad * 4 + j) * H3 + nbase + nt * 16 + l15] = (_Float16)acc[nt][j];
}

// in-place LayerNorm * gw over rows of wx (3072 cols), one row per wave
__global__ __launch_bounds__(256, 1) void k_ln(
    _Float16* __restrict__ wxp, const float* __restrict__ gw)
{
  const int wv = threadIdx.x >> 6, lane = threadIdx.x & 63;
  const size_t row = (size_t)blockIdx.x * 4 + wv;
  _Float16* p = wxp + row * H3 + lane * 8;
  float vals[48];
  float s = 0.f, q = 0.f;
#pragma unroll
  for (int c = 0; c < 6; ++c) {
    const f16x8 v = *(const f16x8*)(p + c * 512);
#pragma unroll
    for (int j = 0; j < 8; ++j) {
      const float f = (float)v[j];
      vals[c * 8 + j] = f; s += f; q += f * f;
    }
  }
#pragma unroll
  for (int m = 1; m < 64; m <<= 1) { s += __shfl_xor(s, m); q += __shfl_xor(q, m); }
  const float mean = s * (1.f / H3);
  const float var  = q * (1.f / H3) - mean * mean;
  const float inv  = rsqrtf(var + LN_EPS);
#pragma unroll
  for (int c = 0; c < 6; ++c) {
    f16x8 o;
#pragma unroll
    for (int j = 0; j < 8; ++j)
      o[j] = (_Float16)((vals[c * 8 + j] - mean) * inv * gw[c * 512 + lane * 8 + j]);
    *(f16x8*)(p + c * 512) = o;
  }
}

// ---------------------------------------------------------------------------
// recurrence: 512 steps, 128 blocks, R11 protocol, block-major hglob
__global__ __launch_bounds__(256, 1) void k_recur(
    const float* __restrict__ R, const float* __restrict__ bx,
    const float* __restrict__ br, const float* __restrict__ gr,
    const _Float16* __restrict__ wx,
    _Float16* __restrict__ hs_out,
    unsigned* __restrict__ hglob,     // h fp16 block-major [128][32][8] as u32
    float* __restrict__ hf32,
    float* __restrict__ pstat,        // [128][64] partial stats
    unsigned* __restrict__ ctrl,
    const unsigned abase,             // l*TT
    const unsigned hbase)             // l*(TT+1)
{
  const int tid = threadIdx.x;
  const int blk = blockIdx.x;
  unsigned* cntA = ctrl;              // 8 lines, word stride 32
  unsigned* cntB = ctrl + 256;        // 8 lines, word stride 32

  __shared__ _Float16 Rs[COLS][HH + 8];
  __shared__ float rhp[2][BBATCH][27];    // K-half partials (odd stride)
  __shared__ float statb[BBATCH][2];
  __shared__ float pred[16][68];          // pstat row-group partials

  const int lane = tid & 63;
  const int wv   = tid >> 6;
  const int mh   = wv >> 1;       // which 16 batch rows
  const int kh   = wv & 1;        // which K half (512)
  const int l15  = lane & 15;
  const int quad = lane >> 4;
  const int kb   = kh * 512;

  // load R slice (cols {i, H+i, 2H+i} for i in [blk*8, blk*8+8)), fp32->fp16
  for (int n = 0; n < COLS; ++n) {
    const int gc = (n >> 3) * HH + blk * HPB + (n & 7);
    for (int k = tid; k < HH; k += 256)
      Rs[n][k] = (_Float16)R[(size_t)k * H3 + gc];
  }

  // per-thread gate ownership: (batch row, h-index)
  const int b_row = tid >> 3;
  const int jj    = tid & 7;
  const int gi    = blk * HPB + jj;
  const float bxz = bx[gi], bxr = bx[HH + gi], bxg = bx[2 * HH + gi];
  const float brz = br[gi], brr = br[HH + gi], brg = br[2 * HH + gi];
  const float grz = gr[gi], grr = gr[HH + gi], grg = gr[2 * HH + gi];
  float hloc = hf32[b_row * HH + gi];

  // initial coherent publish of own h slice (block-major, sc1 u32 pairs)
  {
    union { _Float16 f; unsigned short s; } hc; hc.f = (_Float16)hloc;
    const unsigned short mybits = hc.s;
    const unsigned short pbits  = (unsigned short)__shfl_xor((int)mybits, 1);
    if ((jj & 1) == 0) {
      const unsigned w = (unsigned)mybits | ((unsigned)pbits << 16);
      ASTORE(&hglob[blk * 128 + b_row * 4 + (jj >> 1)], w);
    }
  }
  asm volatile("s_waitcnt vmcnt(0)" ::: "memory");   // wave-local drain
  if (lane == 0) AADD(&cntB[(blk & 7) * 32]);

  // consumer base: block-major chunk (kh*64 + quad), row (mh*16 + l15)
  const _Float16* hread = (const _Float16*)hglob;
  const _Float16* hrow  = hread + (size_t)(kh * 64 + quad) * 256
                                + (size_t)(mh * 16 + l15) * 8;
  const int n1 = 16 + (l15 & 7);          // ntile1 row (lanes >=8 read dup, masked)

  for (int t = 0; t < TT; ++t) {
    // prefetch phase-2 wx operands (t-only dependence; L2-resident)
    const _Float16* wrow = wx + (size_t)(b_row * TT + t) * H3;
    const float wz = (float)wrow[gi];
    const float wr = (float)wrow[HH + gi];
    const float wg = (float)wrow[2 * HH + gi];

    // ---- wait for all 512 wave h-publishes (8 sharded lines, tight poll)
    if (tid < 8) {
      const unsigned* p = cntB + tid * 32;
      const unsigned tgt = 64u * (hbase + (unsigned)t + 1u);
      int spins = 0;
      while (ALOAD(p) < tgt) { if (++spins > (1 << 24)) break; }
    }
    __syncthreads();                                   // barrier 1

    // ---- phase 1: 16 LLC-coherent A loads fully in flight, then MFMA
    f16x8 af[16];
#pragma unroll
    for (int ks = 0; ks < 16; ++ks)
      af[ks] = ldg_h16(hrow + ks * 1024);              // +4 blocks per ks
    asm volatile("s_waitcnt vmcnt(0)" ::: "memory");
    f32x4 acc0 = {0.f,0.f,0.f,0.f}, acc1 = {0.f,0.f,0.f,0.f};
#pragma unroll
    for (int ks = 0; ks < 16; ++ks) {
      const f16x8 b0 = *(const f16x8*)(&Rs[l15][kb + ks * 32 + quad * 8]);
      acc0 = __builtin_amdgcn_mfma_f32_16x16x32_f16(af[ks], b0, acc0, 0, 0, 0);
      const f16x8 b1 = *(const f16x8*)(&Rs[n1][kb + ks * 32 + quad * 8]);
      acc1 = __builtin_amdgcn_mfma_f32_16x16x32_f16(af[ks], b1, acc1, 0, 0, 0);
    }
    // write K-half partials (C layout: row=quad*4+j, col=l15)
#pragma unroll
    for (int j = 0; j < 4; ++j) {
      rhp[kh][mh * 16 + quad * 4 + j][l15] = acc0[j];
      if (l15 < 8) rhp[kh][mh * 16 + quad * 4 + j][16 + l15] = acc1[j];
    }
    __syncthreads();                                   // barrier 2

    // ---- combine K halves; per-row LN partial stats (8-thread shfl reduce)
    const float rz = rhp[0][b_row][jj]      + rhp[1][b_row][jj];
    const float rr = rhp[0][b_row][8 + jj]  + rhp[1][b_row][8 + jj];
    const float rg = rhp[0][b_row][16 + jj] + rhp[1][b_row][16 + jj];
    {
      float s = rz + rr + rg;
      float q = rz * rz + rr * rr + rg * rg;
      s += __shfl_xor(s, 1); q += __shfl_xor(q, 1);
      s += __shfl_xor(s, 2); q += __shfl_xor(q, 2);
      s += __shfl_xor(s, 4); q += __shfl_xor(q, 4);
      if (jj == 0) { statb[b_row][0] = s; statb[b_row][1] = q; }
    }
    __syncthreads();                                   // barrier 3
    // publish pstat (wave 0 only; wave-local drain orders add after data)
    if (tid < 64) ASTORE(&pstat[blk * 64 + tid], statb[tid >> 1][tid & 1]);
    asm volatile("s_waitcnt vmcnt(0)" ::: "memory");
    if (tid == 0) AADD(&cntA[(blk & 7) * 32]);

    // ---- wait for all 128 pstat publishes (8 sharded lines)
    if (tid < 8) {
      const unsigned* p = cntA + tid * 32;
      const unsigned tgt = 16u * (abase + (unsigned)t + 1u);
      int spins = 0;
      while (ALOAD(p) < tgt) { if (++spins > (1 << 24)) break; }
    }
    __syncthreads();                                   // barrier 4

    // ---- flat allreduce: 8 coalesced bypass dwordx4 loads, all in flight
    {
      const int prow0 = tid >> 4;          // 0..15
      const int pcol  = (tid & 15) * 4;    // 0..60
      f32x4 pv0 = ldg_f32x4(pstat + (size_t)(prow0      ) * 64 + pcol);
      f32x4 pv1 = ldg_f32x4(pstat + (size_t)(prow0 +  16) * 64 + pcol);
      f32x4 pv2 = ldg_f32x4(pstat + (size_t)(prow0 +  32) * 64 + pcol);
      f32x4 pv3 = ldg_f32x4(pstat + (size_t)(prow0 +  48) * 64 + pcol);
      f32x4 pv4 = ldg_f32x4(pstat + (size_t)(prow0 +  64) * 64 + pcol);
      f32x4 pv5 = ldg_f32x4(pstat + (size_t)(prow0 +  80) * 64 + pcol);
      f32x4 pv6 = ldg_f32x4(pstat + (size_t)(prow0 +  96) * 64 + pcol);
      f32x4 pv7 = ldg_f32x4(pstat + (size_t)(prow0 + 112) * 64 + pcol);
      asm volatile("s_waitcnt vmcnt(0)" ::: "memory");
      const f32x4 pa = ((pv0 + pv1) + (pv2 + pv3)) + ((pv4 + pv5) + (pv6 + pv7));
      *(f32x4*)(&pred[prow0][pcol]) = pa;
    }
    __syncthreads();                                   // barrier 5
    // broadcast-read finish: 16 group-partials for own row (same-addr bcast)
    float sfs = 0.f, sfq = 0.f;
#pragma unroll
    for (int g = 0; g < 16; ++g) {
      sfs += pred[g][2 * b_row];
      sfq += pred[g][2 * b_row + 1];
    }

    // ---- phase 2: finalize LN, gates, h update
    const float mean = sfs * (1.f / H3);
    const float var  = sfq * (1.f / H3) - mean * mean;
    const float inv  = __frsqrt_rn(var + LN_EPS);
    const float rzn = (rz - mean) * inv * grz;
    const float rrn = (rr - mean) * inv * grr;
    const float rgn = (rg - mean) * inv * grg;
    const float zg    = sigf(wz + bxz + rzn + brz);
    const float rgate = sigf(wr + bxr + rrn + brr);
    const float gg    = tanhfast(wg + bxg + rgate * (rgn + brg));
    const float hn = zg * hloc + (1.f - zg) * gg;
    hloc = hn;
    union { _Float16 f; unsigned short s; } hc; hc.f = (_Float16)hn;
    const unsigned short mybits = hc.s;
    const unsigned short pbits  = (unsigned short)__shfl_xor((int)mybits, 1);
    if ((jj & 1) == 0) {
      const unsigned w = (unsigned)mybits | ((unsigned)pbits << 16);
      ASTORE(&hglob[blk * 128 + b_row * 4 + (jj >> 1)], w);   // block-major publish
    }
    hs_out[(size_t)(b_row * TT + t) * HH + gi] = hc.f;        // L2-cached
    asm volatile("s_waitcnt vmcnt(0)" ::: "memory");          // wave-local drain
    if (lane == 0) AADD(&cntB[(blk & 7) * 32]);               // per-wave flag
  }
  hf32[b_row * HH + gi] = hloc;   // fp32 handoff to next layer (cached)
}

// ---------------------------------------------------------------------------
// out[16384][80] = tanh(hs @ Wlin + blin)
__global__ __launch_bounds__(256, 1) void k_proj(
    const _Float16* __restrict__ hs,
    const _Float16* __restrict__ Wlb,   // [80][1024] fp16
    const float* __restrict__ blin,
    float* __restrict__ out)
{
  const int tid = threadIdx.x, lane = tid & 63, wv = tid >> 6;
  const int l15 = lane & 15, quad = lane >> 4;
  const int mbase = blockIdx.x * 64 + wv * 16;
  f32x4 acc[5] = {{0.f,0.f,0.f,0.f},{0.f,0.f,0.f,0.f},{0.f,0.f,0.f,0.f},
                  {0.f,0.f,0.f,0.f},{0.f,0.f,0.f,0.f}};
  const _Float16* arow = hs + (size_t)(mbase + l15) * HH + quad * 8;
  for (int kc = 0; kc < HH; kc += 32) {
    const f16x8 af = *(const f16x8*)(arow + kc);
#pragma unroll
    for (int nt = 0; nt < 5; ++nt) {
      const f16x8 bv = *(const f16x8*)(Wlb + (size_t)(nt * 16 + l15) * HH + kc + quad * 8);
      acc[nt] = __builtin_amdgcn_mfma_f32_16x16x32_f16(af, bv, acc[nt], 0, 0, 0);
    }
  }
#pragma unroll
  for (int nt = 0; nt < 5; ++nt)
#pragma unroll
    for (int j = 0; j < 4; ++j) {
      const int col = nt * 16 + l15;
      out[(size_t)(mbase + quad * 4 + j) * 80 + col] = tanhf(acc[nt][j] + blin[col]);
    }
}

// ---------------------------------------------------------------------------
extern "C" void kernel_launch(void* const* d_in, const int* in_sizes, int n_in,
                              void* d_out, int out_size, void* d_ws, size_t ws_size,
                              hipStream_t stream)
{
  const float* x    = (const float*)d_in[0];
  const float* W0   = (const float*)d_in[1];
  const float* R0   = (const float*)d_in[2];
  const float* bx0  = (const float*)d_in[3];
  const float* br0  = (const float*)d_in[4];
  const float* gw0  = (const float*)d_in[5];
  const float* gr0  = (const float*)d_in[6];
  const float* Wk   = (const float*)d_in[7];
  const float* Rk   = (const float*)d_in[8];
  const float* bxk  = (const float*)d_in[9];
  const float* brk  = (const float*)d_in[10];
  const float* gwk  = (const float*)d_in[11];
  const float* grk  = (const float*)d_in[12];
  const float* Wlin = (const float*)d_in[13];
  const float* blin = (const float*)d_in[14];

  char* ws = (char*)d_ws;
  unsigned*  ctrl   = (unsigned*)(ws + OFF_CTRL);
  float*     pstat  = (float*)(ws + OFF_PSTAT);
  unsigned*  hglob  = (unsigned*)(ws + OFF_H);
  float*     hf32   = (float*)(ws + OFF_HF);
  _Float16*  Wlb    = (_Float16*)(ws + OFF_WLB);
  _Float16*  Wb     = (_Float16*)(ws + OFF_WB);
  _Float16*  xb     = (_Float16*)(ws + OFF_XBF);
  _Float16*  wx     = (_Float16*)(ws + OFF_WX);
  _Float16*  hsA    = (_Float16*)(ws + OFF_HSA);
  _Float16*  hsB    = (_Float16*)(ws + OFF_HSB);

  hipMemsetAsync(d_ws, 0, CTRL_BYTES, stream);   // counters, pstat, h state

  k_init<<<2048, 256, 0, stream>>>(x, xb, Wlin, Wlb);

  for (int l = 0; l < 3; ++l) {
    const int K = l ? HH : 128;
    const float* Wl  = l ? (Wk  + (size_t)(l - 1) * HH * H3) : W0;
    const float* Rl  = l ? (Rk  + (size_t)(l - 1) * HH * H3) : R0;
    const float* bxl = l ? (bxk + (size_t)(l - 1) * H3) : bx0;
    const float* brl = l ? (brk + (size_t)(l - 1) * H3) : br0;
    const float* gwl = l ? (gwk + (size_t)(l - 1) * H3) : gw0;
    const float* grl = l ? (grk + (size_t)(l - 1) * H3) : gr0;
    const _Float16* Ain = (l == 0) ? xb : ((l == 1) ? hsA : hsB);
    _Float16* hs_out = (l == 1) ? hsB : hsA;

    k_convW<<<H3, 256, 0, stream>>>(Wl, Wb, K);
    k_gemm<<<12288, 256, 0, stream>>>(Ain, Wb, wx, K);
    k_ln<<<4096, 256, 0, stream>>>(wx, gwl);
    k_recur<<<NBLK_R, 256, 0, stream>>>(Rl, bxl, brl, grl, wx, hs_out,
                                        hglob, hf32, pstat, ctrl,
                                        (unsigned)l * (unsigned)TT,
                                        (unsigned)l * (TT + 1u));
  }
  k_proj<<<256, 256, 0, stream>>>(hsA, Wlb, blin, (float*)d_out);
}

// Round 9
// 10771.986 us; speedup vs baseline: 3.3163x; 1.0327x over previous
//
#include <hip/hip_runtime.h>

// ---------------------------------------------------------------------------
// 3-layer LayerNorm-GRU (haste style), B=32 T=512 IN=128 H=1024 OUT=80
// Round 15: R14 (proven 3500us/layer) + 32-line counter sharding.
//   Counter RMW queues were the largest identified residual: cntB had 512
//   per-wave adds over 8 lines = 64 RMWs/line/step (~0.75us paid by the
//   last arriver, every step, on the critical h hop). Now:
//   - cntB sharded over 32 lines, line = (blk&7)*4 + wv -> 16 adds/line.
//   - cntA sharded over 32 lines, line = blk&31        -> 4 adds/line.
//   - polls widened to tid<32 (one line per lane, same parallel cost).
//   - ctrl region 8KB; pstat/hglob/hf32 offsets shifted.
//   Everything else bit-identical to R14 (block-major hglob, LDS-staged
//   stats path, 5 barriers/step, sc1 publish -> wave vmcnt -> add).
// ---------------------------------------------------------------------------

typedef float    f32x4 __attribute__((ext_vector_type(4)));
typedef _Float16 f16x8 __attribute__((ext_vector_type(8)));

#define HH      1024
#define TT      512
#define BBATCH  32
#define H3      3072
#define MROWS   16384      // B*T
#define NBLK_R  128        // compute blocks
#define HPB     8          // h-indices per recurrence block
#define COLS    24         // 3*HPB columns of R per block
#define LN_EPS  1e-5f

// workspace layout (bytes)
#define OFF_CTRL   0u                 // cntA 32 lines @0, cntB 32 lines @4096
#define OFF_PSTAT  8192u              // pstat[128][64] f32 = 32 KB (ends 40960)
#define OFF_H      40960u             // h fp16 block-major [128][32][8] = 64 KB
#define OFF_HF     106496u            // h fp32 [32][1024] = 128 KB (ends 237568)
#define CTRL_BYTES 237568u            // memset region
#define OFF_WLB    327680u            // Wlin^T fp16 [80][1024]  = 160 KB
#define OFF_WB     524288u            // W^T fp16 [3072][K<=1024] = 6 MB
#define OFF_XBF    (8ull<<20)         // x fp16 [16384][128]     = 4 MB
#define OFF_WX     (16ull<<20)        // wx fp16 [16384][3072]   = 96 MB
#define OFF_HSA    (112ull<<20)       // hs fp16 [16384][1024]   = 32 MB
#define OFF_HSB    (144ull<<20)       // hs fp16 [16384][1024]   = 32 MB  (end 176 MB)

#define ALOAD(p)    __hip_atomic_load((p),  __ATOMIC_RELAXED, __HIP_MEMORY_SCOPE_AGENT)
#define ASTORE(p,v) __hip_atomic_store((p), (v), __ATOMIC_RELAXED, __HIP_MEMORY_SCOPE_AGENT)
#define AADD(p)     __hip_atomic_fetch_add((p), 1u, __ATOMIC_RELAXED, __HIP_MEMORY_SCOPE_AGENT)

// LLC-coherent loads (bypass L1 via sc0, L2 via sc1); caller waits vmcnt
__device__ __forceinline__ f16x8 ldg_h16(const _Float16* p) {
  f16x8 r;
  asm volatile("global_load_dwordx4 %0, %1, off sc0 sc1" : "=v"(r) : "v"(p));
  return r;
}
__device__ __forceinline__ f32x4 ldg_f32x4(const float* p) {
  f32x4 r;
  asm volatile("global_load_dwordx4 %0, %1, off sc0 sc1" : "=v"(r) : "v"(p));
  return r;
}

__device__ __forceinline__ float sigf(float x) {
  return __builtin_amdgcn_rcpf(1.f + __expf(-x));
}
__device__ __forceinline__ float tanhfast(float x) {
  const float e2 = __expf(2.f * x);
  return 1.f - 2.f * __builtin_amdgcn_rcpf(e2 + 1.f);
}

// ---------------------------------------------------------------------------
// init: x fp32 -> fp16 ; Wlin [1024][80] -> Wlb^T fp16 [80][1024]
__global__ __launch_bounds__(256, 1) void k_init(
    const float* __restrict__ x, _Float16* __restrict__ xb,
    const float* __restrict__ Wlin, _Float16* __restrict__ Wlb)
{
  const size_t stride = (size_t)gridDim.x * 256;
  for (size_t i = (size_t)blockIdx.x * 256 + threadIdx.x; i < (size_t)MROWS * 128; i += stride)
    xb[i] = (_Float16)x[i];
  for (size_t i = (size_t)blockIdx.x * 256 + threadIdx.x; i < 80u * 1024u; i += stride) {
    const size_t n = i >> 10, k = i & 1023u;
    Wlb[i] = (_Float16)Wlin[k * 80 + n];
  }
}

// W fp32 [K][3072] -> Wb fp16 [3072][K] (n-major for B-fragments)
__global__ __launch_bounds__(256, 1) void k_convW(
    const float* __restrict__ W, _Float16* __restrict__ Wb, const int K)
{
  const int n = blockIdx.x;
  for (int k = threadIdx.x; k < K; k += 256)
    Wb[(size_t)n * K + k] = (_Float16)W[(size_t)k * H3 + n];
}

// Cw[16384][3072] (fp16, raw pre-LN) = A[16384][K] @ W[K][3072]
__global__ __launch_bounds__(256, 1) void k_gemm(
    const _Float16* __restrict__ A,
    const _Float16* __restrict__ Bw,   // [3072][K]
    _Float16* __restrict__ Cw,
    const int K)
{
  __shared__ _Float16 Bs[64][40];
  const int tid = threadIdx.x;
  const int lane = tid & 63, wv = tid >> 6;
  const int l15 = lane & 15, quad = lane >> 4;
  const int tilem = blockIdx.x / 48, tilen = blockIdx.x % 48;
  const int mbase = tilem * 64 + wv * 16;
  const size_t nbase = (size_t)tilen * 64;
  f32x4 acc[4] = {{0.f,0.f,0.f,0.f},{0.f,0.f,0.f,0.f},{0.f,0.f,0.f,0.f},{0.f,0.f,0.f,0.f}};
  const _Float16* arow = A + (size_t)(mbase + l15) * K + quad * 8;
  const int sn = tid >> 2, sk = (tid & 3) * 8;
  const _Float16* bsrc = Bw + (nbase + sn) * K + sk;
  for (int kc = 0; kc < K; kc += 32) {
    __syncthreads();
    *(f16x8*)(&Bs[sn][sk]) = *(const f16x8*)(bsrc + kc);
    __syncthreads();
    const f16x8 af = *(const f16x8*)(arow + kc);
#pragma unroll
    for (int nt = 0; nt < 4; ++nt) {
      const f16x8 bv = *(const f16x8*)(&Bs[nt * 16 + l15][quad * 8]);
      acc[nt] = __builtin_amdgcn_mfma_f32_16x16x32_f16(af, bv, acc[nt], 0, 0, 0);
    }
  }
#pragma unroll
  for (int nt = 0; nt < 4; ++nt)
#pragma unroll
    for (int j = 0; j < 4; ++j)
      Cw[(size_t)(mbase + quad * 4 + j) * H3 + nbase + nt * 16 + l15] = (_Float16)acc[nt][j];
}

// in-place LayerNorm * gw over rows of wx (3072 cols), one row per wave
__global__ __launch_bounds__(256, 1) void k_ln(
    _Float16* __restrict__ wxp, const float* __restrict__ gw)
{
  const int wv = threadIdx.x >> 6, lane = threadIdx.x & 63;
  const size_t row = (size_t)blockIdx.x * 4 + wv;
  _Float16* p = wxp + row * H3 + lane * 8;
  float vals[48];
  float s = 0.f, q = 0.f;
#pragma unroll
  for (int c = 0; c < 6; ++c) {
    const f16x8 v = *(const f16x8*)(p + c * 512);
#pragma unroll
    for (int j = 0; j < 8; ++j) {
      const float f = (float)v[j];
      vals[c * 8 + j] = f; s += f; q += f * f;
    }
  }
#pragma unroll
  for (int m = 1; m < 64; m <<= 1) { s += __shfl_xor(s, m); q += __shfl_xor(q, m); }
  const float mean = s * (1.f / H3);
  const float var  = q * (1.f / H3) - mean * mean;
  const float inv  = rsqrtf(var + LN_EPS);
#pragma unroll
  for (int c = 0; c < 6; ++c) {
    f16x8 o;
#pragma unroll
    for (int j = 0; j < 8; ++j)
      o[j] = (_Float16)((vals[c * 8 + j] - mean) * inv * gw[c * 512 + lane * 8 + j]);
    *(f16x8*)(p + c * 512) = o;
  }
}

// ---------------------------------------------------------------------------
// recurrence: 512 steps, 128 blocks, R14 protocol, 32-line counter shards
__global__ __launch_bounds__(256, 1) void k_recur(
    const float* __restrict__ R, const float* __restrict__ bx,
    const float* __restrict__ br, const float* __restrict__ gr,
    const _Float16* __restrict__ wx,
    _Float16* __restrict__ hs_out,
    unsigned* __restrict__ hglob,     // h fp16 block-major [128][32][8] as u32
    float* __restrict__ hf32,
    float* __restrict__ pstat,        // [128][64] partial stats
    unsigned* __restrict__ ctrl,
    const unsigned abase,             // l*TT
    const unsigned hbase)             // l*(TT+1)
{
  const int tid = threadIdx.x;
  const int blk = blockIdx.x;
  unsigned* cntA = ctrl;              // 32 lines, word stride 32 (4 adds/line)
  unsigned* cntB = ctrl + 1024;       // 32 lines, word stride 32 (16 adds/line)

  __shared__ _Float16 Rs[COLS][HH + 8];
  __shared__ float rhp[2][BBATCH][27];    // K-half partials (odd stride)
  __shared__ float statb[BBATCH][2];
  __shared__ float pred[16][68];          // pstat row-group partials

  const int lane = tid & 63;
  const int wv   = tid >> 6;
  const int mh   = wv >> 1;       // which 16 batch rows
  const int kh   = wv & 1;        // which K half (512)
  const int l15  = lane & 15;
  const int quad = lane >> 4;
  const int kb   = kh * 512;
  const int lineB = ((blk & 7) * 4 + wv) * 32;   // cntB shard for this wave

  // load R slice (cols {i, H+i, 2H+i} for i in [blk*8, blk*8+8)), fp32->fp16
  for (int n = 0; n < COLS; ++n) {
    const int gc = (n >> 3) * HH + blk * HPB + (n & 7);
    for (int k = tid; k < HH; k += 256)
      Rs[n][k] = (_Float16)R[(size_t)k * H3 + gc];
  }

  // per-thread gate ownership: (batch row, h-index)
  const int b_row = tid >> 3;
  const int jj    = tid & 7;
  const int gi    = blk * HPB + jj;
  const float bxz = bx[gi], bxr = bx[HH + gi], bxg = bx[2 * HH + gi];
  const float brz = br[gi], brr = br[HH + gi], brg = br[2 * HH + gi];
  const float grz = gr[gi], grr = gr[HH + gi], grg = gr[2 * HH + gi];
  float hloc = hf32[b_row * HH + gi];

  // initial coherent publish of own h slice (block-major, sc1 u32 pairs)
  {
    union { _Float16 f; unsigned short s; } hc; hc.f = (_Float16)hloc;
    const unsigned short mybits = hc.s;
    const unsigned short pbits  = (unsigned short)__shfl_xor((int)mybits, 1);
    if ((jj & 1) == 0) {
      const unsigned w = (unsigned)mybits | ((unsigned)pbits << 16);
      ASTORE(&hglob[blk * 128 + b_row * 4 + (jj >> 1)], w);
    }
  }
  asm volatile("s_waitcnt vmcnt(0)" ::: "memory");   // wave-local drain
  if (lane == 0) AADD(&cntB[lineB]);

  // consumer base: block-major chunk (kh*64 + quad), row (mh*16 + l15)
  const _Float16* hread = (const _Float16*)hglob;
  const _Float16* hrow  = hread + (size_t)(kh * 64 + quad) * 256
                                + (size_t)(mh * 16 + l15) * 8;
  const int n1 = 16 + (l15 & 7);          // ntile1 row (lanes >=8 read dup, masked)

  for (int t = 0; t < TT; ++t) {
    // prefetch phase-2 wx operands (t-only dependence; L2-resident)
    const _Float16* wrow = wx + (size_t)(b_row * TT + t) * H3;
    const float wz = (float)wrow[gi];
    const float wr = (float)wrow[HH + gi];
    const float wg = (float)wrow[2 * HH + gi];

    // ---- wait for all 512 wave h-publishes (32 sharded lines, tight poll)
    if (tid < 32) {
      const unsigned* p = cntB + tid * 32;
      const unsigned tgt = 16u * (hbase + (unsigned)t + 1u);
      int spins = 0;
      while (ALOAD(p) < tgt) { if (++spins > (1 << 24)) break; }
    }
    __syncthreads();                                   // barrier 1

    // ---- phase 1: 16 LLC-coherent A loads fully in flight, then MFMA
    f16x8 af[16];
#pragma unroll
    for (int ks = 0; ks < 16; ++ks)
      af[ks] = ldg_h16(hrow + ks * 1024);              // +4 blocks per ks
    asm volatile("s_waitcnt vmcnt(0)" ::: "memory");
    f32x4 acc0 = {0.f,0.f,0.f,0.f}, acc1 = {0.f,0.f,0.f,0.f};
#pragma unroll
    for (int ks = 0; ks < 16; ++ks) {
      const f16x8 b0 = *(const f16x8*)(&Rs[l15][kb + ks * 32 + quad * 8]);
      acc0 = __builtin_amdgcn_mfma_f32_16x16x32_f16(af[ks], b0, acc0, 0, 0, 0);
      const f16x8 b1 = *(const f16x8*)(&Rs[n1][kb + ks * 32 + quad * 8]);
      acc1 = __builtin_amdgcn_mfma_f32_16x16x32_f16(af[ks], b1, acc1, 0, 0, 0);
    }
    // write K-half partials (C layout: row=quad*4+j, col=l15)
#pragma unroll
    for (int j = 0; j < 4; ++j) {
      rhp[kh][mh * 16 + quad * 4 + j][l15] = acc0[j];
      if (l15 < 8) rhp[kh][mh * 16 + quad * 4 + j][16 + l15] = acc1[j];
    }
    __syncthreads();                                   // barrier 2

    // ---- combine K halves; per-row LN partial stats (8-thread shfl reduce)
    const float rz = rhp[0][b_row][jj]      + rhp[1][b_row][jj];
    const float rr = rhp[0][b_row][8 + jj]  + rhp[1][b_row][8 + jj];
    const float rg = rhp[0][b_row][16 + jj] + rhp[1][b_row][16 + jj];
    {
      float s = rz + rr + rg;
      float q = rz * rz + rr * rr + rg * rg;
      s += __shfl_xor(s, 1); q += __shfl_xor(q, 1);
      s += __shfl_xor(s, 2); q += __shfl_xor(q, 2);
      s += __shfl_xor(s, 4); q += __shfl_xor(q, 4);
      if (jj == 0) { statb[b_row][0] = s; statb[b_row][1] = q; }
    }
    __syncthreads();                                   // barrier 3
    // publish pstat (wave 0 only; wave-local drain orders add after data)
    if (tid < 64) ASTORE(&pstat[blk * 64 + tid], statb[tid >> 1][tid & 1]);
    asm volatile("s_waitcnt vmcnt(0)" ::: "memory");
    if (tid == 0) AADD(&cntA[(blk & 31) * 32]);

    // ---- wait for all 128 pstat publishes (32 sharded lines)
    if (tid < 32) {
      const unsigned* p = cntA + tid * 32;
      const unsigned tgt = 4u * (abase + (unsigned)t + 1u);
      int spins = 0;
      while (ALOAD(p) < tgt) { if (++spins > (1 << 24)) break; }
    }
    __syncthreads();                                   // barrier 4

    // ---- flat allreduce: 8 coalesced bypass dwordx4 loads, all in flight
    {
      const int prow0 = tid >> 4;          // 0..15
      const int pcol  = (tid & 15) * 4;    // 0..60
      f32x4 pv0 = ldg_f32x4(pstat + (size_t)(prow0      ) * 64 + pcol);
      f32x4 pv1 = ldg_f32x4(pstat + (size_t)(prow0 +  16) * 64 + pcol);
      f32x4 pv2 = ldg_f32x4(pstat + (size_t)(prow0 +  32) * 64 + pcol);
      f32x4 pv3 = ldg_f32x4(pstat + (size_t)(prow0 +  48) * 64 + pcol);
      f32x4 pv4 = ldg_f32x4(pstat + (size_t)(prow0 +  64) * 64 + pcol);
      f32x4 pv5 = ldg_f32x4(pstat + (size_t)(prow0 +  80) * 64 + pcol);
      f32x4 pv6 = ldg_f32x4(pstat + (size_t)(prow0 +  96) * 64 + pcol);
      f32x4 pv7 = ldg_f32x4(pstat + (size_t)(prow0 + 112) * 64 + pcol);
      asm volatile("s_waitcnt vmcnt(0)" ::: "memory");
      const f32x4 pa = ((pv0 + pv1) + (pv2 + pv3)) + ((pv4 + pv5) + (pv6 + pv7));
      *(f32x4*)(&pred[prow0][pcol]) = pa;
    }
    __syncthreads();                                   // barrier 5
    // broadcast-read finish: 16 group-partials for own row (same-addr bcast)
    float sfs = 0.f, sfq = 0.f;
#pragma unroll
    for (int g = 0; g < 16; ++g) {
      sfs += pred[g][2 * b_row];
      sfq += pred[g][2 * b_row + 1];
    }

    // ---- phase 2: finalize LN, gates, h update
    const float mean = sfs * (1.f / H3);
    const float var  = sfq * (1.f / H3) - mean * mean;
    const float inv  = __frsqrt_rn(var + LN_EPS);
    const float rzn = (rz - mean) * inv * grz;
    const float rrn = (rr - mean) * inv * grr;
    const float rgn = (rg - mean) * inv * grg;
    const float zg    = sigf(wz + bxz + rzn + brz);
    const float rgate = sigf(wr + bxr + rrn + brr);
    const float gg    = tanhfast(wg + bxg + rgate * (rgn + brg));
    const float hn = zg * hloc + (1.f - zg) * gg;
    hloc = hn;
    union { _Float16 f; unsigned short s; } hc; hc.f = (_Float16)hn;
    const unsigned short mybits = hc.s;
    const unsigned short pbits  = (unsigned short)__shfl_xor((int)mybits, 1);
    if ((jj & 1) == 0) {
      const unsigned w = (unsigned)mybits | ((unsigned)pbits << 16);
      ASTORE(&hglob[blk * 128 + b_row * 4 + (jj >> 1)], w);   // block-major publish
    }
    hs_out[(size_t)(b_row * TT + t) * HH + gi] = hc.f;        // L2-cached
    asm volatile("s_waitcnt vmcnt(0)" ::: "memory");          // wave-local drain
    if (lane == 0) AADD(&cntB[lineB]);                        // per-wave flag
  }
  hf32[b_row * HH + gi] = hloc;   // fp32 handoff to next layer (cached)
}

// ---------------------------------------------------------------------------
// out[16384][80] = tanh(hs @ Wlin + blin)
__global__ __launch_bounds__(256, 1) void k_proj(
    const _Float16* __restrict__ hs,
    const _Float16* __restrict__ Wlb,   // [80][1024] fp16
    const float* __restrict__ blin,
    float* __restrict__ out)
{
  const int tid = threadIdx.x, lane = tid & 63, wv = tid >> 6;
  const int l15 = lane & 15, quad = lane >> 4;
  const int mbase = blockIdx.x * 64 + wv * 16;
  f32x4 acc[5] = {{0.f,0.f,0.f,0.f},{0.f,0.f,0.f,0.f},{0.f,0.f,0.f,0.f},
                  {0.f,0.f,0.f,0.f},{0.f,0.f,0.f,0.f}};
  const _Float16* arow = hs + (size_t)(mbase + l15) * HH + quad * 8;
  for (int kc = 0; kc < HH; kc += 32) {
    const f16x8 af = *(const f16x8*)(arow + kc);
#pragma unroll
    for (int nt = 0; nt < 5; ++nt) {
      const f16x8 bv = *(const f16x8*)(Wlb + (size_t)(nt * 16 + l15) * HH + kc + quad * 8);
      acc[nt] = __builtin_amdgcn_mfma_f32_16x16x32_f16(af, bv, acc[nt], 0, 0, 0);
    }
  }
#pragma unroll
  for (int nt = 0; nt < 5; ++nt)
#pragma unroll
    for (int j = 0; j < 4; ++j) {
      const int col = nt * 16 + l15;
      out[(size_t)(mbase + quad * 4 + j) * 80 + col] = tanhf(acc[nt][j] + blin[col]);
    }
}

// ---------------------------------------------------------------------------
extern "C" void kernel_launch(void* const* d_in, const int* in_sizes, int n_in,
                              void* d_out, int out_size, void* d_ws, size_t ws_size,
                              hipStream_t stream)
{
  const float* x    = (const float*)d_in[0];
  const float* W0   = (const float*)d_in[1];
  const float* R0   = (const float*)d_in[2];
  const float* bx0  = (const float*)d_in[3];
  const float* br0  = (const float*)d_in[4];
  const float* gw0  = (const float*)d_in[5];
  const float* gr0  = (const float*)d_in[6];
  const float* Wk   = (const float*)d_in[7];
  const float* Rk   = (const float*)d_in[8];
  const float* bxk  = (const float*)d_in[9];
  const float* brk  = (const float*)d_in[10];
  const float* gwk  = (const float*)d_in[11];
  const float* grk  = (const float*)d_in[12];
  const float* Wlin = (const float*)d_in[13];
  const float* blin = (const float*)d_in[14];

  char* ws = (char*)d_ws;
  unsigned*  ctrl   = (unsigned*)(ws + OFF_CTRL);
  float*     pstat  = (float*)(ws + OFF_PSTAT);
  unsigned*  hglob  = (unsigned*)(ws + OFF_H);
  float*     hf32   = (float*)(ws + OFF_HF);
  _Float16*  Wlb    = (_Float16*)(ws + OFF_WLB);
  _Float16*  Wb     = (_Float16*)(ws + OFF_WB);
  _Float16*  xb     = (_Float16*)(ws + OFF_XBF);
  _Float16*  wx     = (_Float16*)(ws + OFF_WX);
  _Float16*  hsA    = (_Float16*)(ws + OFF_HSA);
  _Float16*  hsB    = (_Float16*)(ws + OFF_HSB);

  hipMemsetAsync(d_ws, 0, CTRL_BYTES, stream);   // counters, pstat, h state

  k_init<<<2048, 256, 0, stream>>>(x, xb, Wlin, Wlb);

  for (int l = 0; l < 3; ++l) {
    const int K = l ? HH : 128;
    const float* Wl  = l ? (Wk  + (size_t)(l - 1) * HH * H3) : W0;
    const float* Rl  = l ? (Rk  + (size_t)(l - 1) * HH * H3) : R0;
    const float* bxl = l ? (bxk + (size_t)(l - 1) * H3) : bx0;
    const float* brl = l ? (brk + (size_t)(l - 1) * H3) : br0;
    const float* gwl = l ? (gwk + (size_t)(l - 1) * H3) : gw0;
    const float* grl = l ? (grk + (size_t)(l - 1) * H3) : gr0;
    const _Float16* Ain = (l == 0) ? xb : ((l == 1) ? hsA : hsB);
    _Float16* hs_out = (l == 1) ? hsB : hsA;

    k_convW<<<H3, 256, 0, stream>>>(Wl, Wb, K);
    k_gemm<<<12288, 256, 0, stream>>>(Ain, Wb, wx, K);
    k_ln<<<4096, 256, 0, stream>>>(wx, gwl);
    k_recur<<<NBLK_R, 256, 0, stream>>>(Rl, bxl, brl, grl, wx, hs_out,
                                        hglob, hf32, pstat, ctrl,
                                        (unsigned)l * (unsigned)TT,
                                        (unsigned)l * (TT + 1u));
  }
  k_proj<<<256, 256, 0, stream>>>(hsA, Wlb, blin, (float*)d_out);
}